// Round 4
// baseline (425.692 us; speedup 1.0000x reference)
//
#include <hip/hip_runtime.h>
#include <math.h>

#define LSEQ 256
#define NB   128

typedef unsigned short u16;
typedef unsigned int   u32;
typedef __attribute__((ext_vector_type(8))) short bf16x8;  // 8 bf16 = 4 VGPR
typedef __attribute__((ext_vector_type(4))) float f32x4;

static __device__ __forceinline__ u16 f2bf(float x) {
    union { float f; u32 u; } v; v.f = x;
    const u32 r = v.u + 0x7fffu + ((v.u >> 16) & 1u);   // RNE
    return (u16)(r >> 16);
}
static __device__ __forceinline__ float bf2f(u16 u) {
    union { u32 i; float f; } v; v.i = ((u32)u) << 16; return v.f;
}
// async global->LDS, 16B per lane, dest = wave-uniform base + lane*16
static __device__ __forceinline__ void glds16(const u16* src, u16* dst) {
    __builtin_amdgcn_global_load_lds(
        (const __attribute__((address_space(1))) u32*)src,
        (__attribute__((address_space(3))) u32*)dst, 16, 0, 0);
}

// ---------------------------------------------------------------------------
// bf16 MFMA GEMM. Block = 128 rows x 256 cols, 512 threads = 8 waves (2x4),
// wave tile 64x64 (4x4 fragments of 16x16x32). BK=64.
// A: bf16 row-major MxK (lda, K mult of 64, padded buffers). glds-staged.
// B: BMODE 0 -> bf16 [N][K] (TB), glds-staged. BMODE 1 -> bf16 [K][N],
//    reg-transpose staged, cols >= Bn read as 0.
// LDS: linear rows of 128B, 8 slots of 16B, XOR-swizzle slot ^= (row&7)
// applied on BOTH stage-source and read (involution, rule #21).
// Epilogue: bias (gc<Nbias), relu, mask (batched), or fused masked row-pool.
// ---------------------------------------------------------------------------
template<int BMODE, bool BIAS, bool RELU, bool MASKE, bool POOLE, bool BATCHED>
__global__ __launch_bounds__(512)
void gemm(const u16* __restrict__ A, int lda, long long sA,
          const u16* __restrict__ B, int ldb, long long sB,
          u16* __restrict__ C, int ldc, long long sC,
          const float* __restrict__ bias, int Nbias,
          const float* __restrict__ m1, const float* __restrict__ m2,
          float* __restrict__ pool, int poolOff, const float* __restrict__ pmask,
          int K, int Bn, int Nwrite)
{
    __shared__ u16 As[128 * 64];   // 16 KB
    __shared__ u16 Bs[256 * 64];   // 32 KB

    const int bz = BATCHED ? blockIdx.z : 0;
    const u16* Ab = A + (long long)bz * sA;
    const u16* Bb = B + (long long)bz * sB;
    const int m0 = blockIdx.y * 128;
    const int n0 = blockIdx.x * 256;
    const int t = threadIdx.x;
    const int lane = t & 63;
    const int w = t >> 6;          // 0..7
    const int wm = w >> 2;         // 0..1
    const int wn = w & 3;          // 0..3
    const int lr = lane & 15;
    const int lg = lane >> 4;      // 0..3

    f32x4 acc[4][4] = {};

    for (int k0 = 0; k0 < K; k0 += 64) {
        // ---- stage A: 16 KB = 16 chunks of 1KB; wave w -> chunks 2w,2w+1
#pragma unroll
        for (int i = 0; i < 2; ++i) {
            const int ch = w * 2 + i;
            const int row = (ch << 3) + (lane >> 3);
            const int slot = (lane & 7) ^ (row & 7);
            glds16(Ab + (long long)(m0 + row) * lda + k0 + (slot << 3),
                   &As[ch << 9]);
        }
        // ---- stage B
        if (BMODE == 0) {
#pragma unroll
            for (int i = 0; i < 4; ++i) {
                const int ch = w * 4 + i;
                const int row = (ch << 3) + (lane >> 3);
                const int slot = (lane & 7) ^ (row & 7);
                glds16(Bb + (long long)(n0 + row) * ldb + k0 + (slot << 3),
                       &Bs[ch << 9]);
            }
        } else {
            // B is [K][N]: thread covers 8k x 4n, transpose in regs
            const int n4 = (t & 63) << 2;    // 0..252
            const int k8 = w << 3;           // 0..56
            union { uint2 q2[8]; u16 s[32]; } uq;
#pragma unroll
            for (int i = 0; i < 8; ++i)
                uq.q2[i] = *reinterpret_cast<const uint2*>(
                    Bb + (long long)(k0 + k8 + i) * ldb + n0 + n4);
#pragma unroll
            for (int j = 0; j < 4; ++j) {
                u32 v0 = 0, v1 = 0, v2 = 0, v3 = 0;
                if (n0 + n4 + j < Bn) {
                    v0 = (u32)uq.s[j]      | ((u32)uq.s[4 + j]  << 16);
                    v1 = (u32)uq.s[8 + j]  | ((u32)uq.s[12 + j] << 16);
                    v2 = (u32)uq.s[16 + j] | ((u32)uq.s[20 + j] << 16);
                    v3 = (u32)uq.s[24 + j] | ((u32)uq.s[28 + j] << 16);
                }
                const int row = n4 + j;
                const int slot = w ^ (row & 7);
                *reinterpret_cast<uint4*>(&Bs[row * 64 + (slot << 3)]) =
                    make_uint4(v0, v1, v2, v3);
            }
        }
        __syncthreads();

        // ---- fragments + MFMA (2 k-halves of 32)
#pragma unroll
        for (int kk = 0; kk < 2; ++kk) {
            bf16x8 af[4], bf[4];
#pragma unroll
            for (int mi = 0; mi < 4; ++mi) {
                const int row = wm * 64 + mi * 16 + lr;
                const int slot = ((kk << 2) + lg) ^ (row & 7);
                af[mi] = *reinterpret_cast<const bf16x8*>(&As[row * 64 + (slot << 3)]);
            }
#pragma unroll
            for (int ni = 0; ni < 4; ++ni) {
                const int row = wn * 64 + ni * 16 + lr;
                const int slot = ((kk << 2) + lg) ^ (row & 7);
                bf[ni] = *reinterpret_cast<const bf16x8*>(&Bs[row * 64 + (slot << 3)]);
            }
#pragma unroll
            for (int mi = 0; mi < 4; ++mi)
#pragma unroll
                for (int ni = 0; ni < 4; ++ni)
                    acc[mi][ni] = __builtin_amdgcn_mfma_f32_16x16x32_bf16(
                        af[mi], bf[ni], acc[mi][ni], 0, 0, 0);
        }
        __syncthreads();
    }

    const int rbase = lg << 2;
    if (!POOLE) {
        u16* Cb = C + (long long)bz * sC;
        float m1v[4][4];
        if (MASKE) {
#pragma unroll
            for (int mi = 0; mi < 4; ++mi)
#pragma unroll
                for (int r = 0; r < 4; ++r)
                    m1v[mi][r] = m1[bz * 256 + m0 + wm * 64 + mi * 16 + rbase + r];
        }
#pragma unroll
        for (int ni = 0; ni < 4; ++ni) {
            const int gc = n0 + wn * 64 + ni * 16 + lr;
            if (gc >= Nwrite) continue;
            float bcv = 0.f;
            if (BIAS) bcv = (gc < Nbias) ? bias[gc] : 0.f;
            float m2v = 0.f;
            if (MASKE) m2v = m2[bz * 256 + gc];
#pragma unroll
            for (int mi = 0; mi < 4; ++mi) {
#pragma unroll
                for (int r = 0; r < 4; ++r) {
                    const long long gr = m0 + wm * 64 + mi * 16 + rbase + r;
                    float x = acc[mi][ni][r];
                    if (BIAS) x += bcv;
                    if (RELU) x = fmaxf(x, 0.f);
                    if (MASKE) x *= m1v[mi][r] * m2v;
                    Cb[gr * ldc + gc] = f2bf(x);
                }
            }
        }
    } else {
        // fused compare epilogue: pooled[b][poolOff+gc] += relu(acc+bc)*mask[row]
        __syncthreads();
        float* pool_s = reinterpret_cast<float*>(As);
        for (int i = t; i < 256; i += 512) pool_s[i] = 0.f;
        __syncthreads();
        const int b = m0 >> 8;
        const float* mk = pmask + b * 256 + (m0 & 255);
        float mrow[4][4];
#pragma unroll
        for (int mi = 0; mi < 4; ++mi)
#pragma unroll
            for (int r = 0; r < 4; ++r)
                mrow[mi][r] = mk[wm * 64 + mi * 16 + rbase + r];
#pragma unroll
        for (int ni = 0; ni < 4; ++ni) {
            const int lc = wn * 64 + ni * 16 + lr;
            const int gc = n0 + lc;
            const float bcv = (BIAS && gc < Nbias) ? bias[gc] : 0.f;
            float cs = 0.f;
#pragma unroll
            for (int mi = 0; mi < 4; ++mi)
#pragma unroll
                for (int r = 0; r < 4; ++r)
                    cs += fmaxf(acc[mi][ni][r] + bcv, 0.f) * mrow[mi][r];
            cs += __shfl_xor(cs, 16, 64);
            cs += __shfl_xor(cs, 32, 64);
            if (lg == 0) atomicAdd(&pool_s[lc], cs);
        }
        __syncthreads();
        for (int i = t; i < 256; i += 512) {
            const int gc = n0 + i;
            if (gc < Nwrite) atomicAdd(&pool[b * 800 + poolOff + gc], pool_s[i]);
        }
    }
}

// ---------------------------------------------------------------------------
// weight prep: dst[n][k] (bf16, [dstRows][dstCols]) = src[srcRow(k)][n] or 0.
// srcRow(k): k<seg1 -> k ; seg2start<=k<seg2start+(srcRows-seg1) -> seg1+(k-seg2start)
// ---------------------------------------------------------------------------
__global__ __launch_bounds__(256)
void prep_w(const float* __restrict__ src, int srcRows, int srcCols,
            u16* __restrict__ dst, int dstCols, int dstTotal,
            int seg1, int seg2start)
{
    const int idx = blockIdx.x * 256 + threadIdx.x;
    if (idx >= dstTotal) return;
    const int n = idx / dstCols, k = idx - n * dstCols;
    int sr = -1;
    if (k < seg1) sr = k;
    else if (k >= seg2start && (k - seg2start) < (srcRows - seg1)) sr = seg1 + (k - seg2start);
    u16 v = 0;
    if (n < srcCols && sr >= 0) v = f2bf(src[(long long)sr * srcCols + n]);
    dst[idx] = v;
}

__global__ __launch_bounds__(256)
void zero_pool(float* __restrict__ p)
{
    p[blockIdx.x * 256 + threadIdx.x] = 0.f;
}

// mask[b][l] = (l < count_nonzero(x[b,:])) ? 1 : 0
__global__ __launch_bounds__(256)
void make_mask(const int* __restrict__ x, float* __restrict__ mask)
{
    const int b = blockIdx.x;
    const int t = threadIdx.x;
    int nz = (x[b * LSEQ + t] != 0) ? 1 : 0;
#pragma unroll
    for (int o = 32; o; o >>= 1) nz += __shfl_xor(nz, o, 64);
    __shared__ int red[4];
    if ((t & 63) == 0) red[t >> 6] = nz;
    __syncthreads();
    const int size = red[0] + red[1] + red[2] + red[3];
    mask[b * LSEQ + t] = (t < size) ? 1.0f : 0.0f;
}

// gather + L2-normalize -> H[row][0:320] bf16 (cols 300-319 zero), pitch 640
__global__ __launch_bounds__(256)
void gather_norm(const int* __restrict__ x, const float* __restrict__ emb,
                 u16* __restrict__ h)
{
    const int t = threadIdx.x;
    const int lane = t & 63;
    const long long row = (long long)blockIdx.x * 4 + (t >> 6);
    const int tok = x[row];
    const float* er = emb + (long long)tok * 300;
    float vals[5];
    float ss = 0.f;
#pragma unroll
    for (int i = 0; i < 5; ++i) {
        const int c = lane + i * 64;
        const float v = (c < 300) ? er[c] : 0.f;
        vals[i] = v;
        ss = fmaf(v, v, ss);
    }
#pragma unroll
    for (int o = 32; o; o >>= 1) ss += __shfl_xor(ss, o, 64);
    const float inv = 1.0f / sqrtf(ss);
    u16* out = h + row * 640;
#pragma unroll
    for (int i = 0; i < 5; ++i) {
        const int c = lane + i * 64;
        out[c] = f2bf(vals[i] * inv);
    }
}

// in-place row softmax over 256 (bf16), optional distance bias
template<bool DBIAS>
__global__ __launch_bounds__(256)
void row_softmax(u16* __restrict__ buf, const float* __restrict__ b_dist)
{
    const long long row = blockIdx.x;
    const int i = (int)(row & 255);
    const int t = threadIdx.x;
    float v = bf2f(buf[row * 256 + t]);
    if (DBIAS) {
        const int d = (i > t) ? (i - t) : (t - i);
        if (d >= 10) v += b_dist[0];
    }
    float m = v;
#pragma unroll
    for (int o = 32; o; o >>= 1) m = fmaxf(m, __shfl_xor(m, o, 64));
    __shared__ float redm[4];
    if ((t & 63) == 0) redm[t >> 6] = m;
    __syncthreads();
    m = fmaxf(fmaxf(redm[0], redm[1]), fmaxf(redm[2], redm[3]));
    const float e = expf(v - m);
    float s = e;
#pragma unroll
    for (int o = 32; o; o >>= 1) s += __shfl_xor(s, o, 64);
    __shared__ float reds[4];
    if ((t & 63) == 0) reds[t >> 6] = s;
    __syncthreads();
    s = reds[0] + reds[1] + reds[2] + reds[3];
    buf[row * 256 + t] = f2bf(e / s);
}

__global__ __launch_bounds__(256)
void final_fc(const float* __restrict__ pooled, const float* __restrict__ Wg,
              const float* __restrict__ bg, float* __restrict__ out)
{
    const int b = blockIdx.x;
    const int t = threadIdx.x;
    float a0 = 0.f, a1 = 0.f, a2 = 0.f;
    for (int k = t; k < 800; k += 256) {
        const float p = pooled[(long long)b * 800 + k];
        a0 = fmaf(p, Wg[k * 3 + 0], a0);
        a1 = fmaf(p, Wg[k * 3 + 1], a1);
        a2 = fmaf(p, Wg[k * 3 + 2], a2);
    }
#pragma unroll
    for (int o = 32; o; o >>= 1) {
        a0 += __shfl_xor(a0, o, 64);
        a1 += __shfl_xor(a1, o, 64);
        a2 += __shfl_xor(a2, o, 64);
    }
    __shared__ float r0[4], r1[4], r2[4];
    if ((t & 63) == 0) { r0[t >> 6] = a0; r1[t >> 6] = a1; r2[t >> 6] = a2; }
    __syncthreads();
    if (t == 0) {
        out[b * 3 + 0] = r0[0] + r0[1] + r0[2] + r0[3] + bg[0];
        out[b * 3 + 1] = r1[0] + r1[1] + r1[2] + r1[3] + bg[1];
        out[b * 3 + 2] = r2[0] + r2[1] + r2[2] + r2[3] + bg[2];
    }
}

// ---------------------------------------------------------------------------
extern "C" void kernel_launch(void* const* d_in, const int* in_sizes, int n_in,
                              void* d_out, int out_size, void* d_ws, size_t ws_size,
                              hipStream_t stream)
{
    (void)in_sizes; (void)n_in; (void)out_size; (void)ws_size;

    const int*   x1     = (const int*)  d_in[0];
    const int*   x2     = (const int*)  d_in[1];
    const float* emb    = (const float*)d_in[2];
    const float* Wi     = (const float*)d_in[3];
    const float* bi     = (const float*)d_in[4];
    const float* b_dist = (const float*)d_in[5];
    const float* Wp     = (const float*)d_in[6];
    const float* bp     = (const float*)d_in[7];
    const float* Wa     = (const float*)d_in[8];
    const float* ba     = (const float*)d_in[9];
    const float* Wc     = (const float*)d_in[10];
    const float* bc     = (const float*)d_in[11];
    const float* Wg     = (const float*)d_in[12];
    const float* bg     = (const float*)d_in[13];
    float* out = (float*)d_out;

    // ---- workspace (bf16 unless noted), all bases 16B-aligned -----------
    u16* wsu  = (u16*)d_ws;
    u16* H    = wsu;               // [32768][640]: e(0:300)|0|xp(320:620)|0
    u16* CMP1 = wsu + 20971520;    // [32768][448]: P1(0:200)|beta(200:400)|0
    u16* CMP2 = wsu + 35651584;    // [32768][448]: P2 | alpha | 0
    u16* F    = wsu + 50331648;    // [32768][256]: f / a1
    u16* ATT  = wsu + 58720256;    // [32768][256]: a2
    u16* SIM  = wsu + 67108864;    // [128][256][256]
    u16* SS   = wsu + 75497472;    // [128][256][256]
    u16* WiT  = wsu + 83886080;    // [256][320]
    u16* WaT  = wsu + 83968000;    // [256][256]
    u16* WpT  = wsu + 84033536;    // [256][640]
    u16* WcT  = wsu + 84197376;    // [512][448]
    float* fb = (float*)(wsu + 84426752);
    float* POOL = fb;              // [128][800]
    float* M1f  = fb + 102400;     // [128][256]
    float* M2f  = fb + 135168;

    const long long sL = 65536;    // 256*256 per-batch stride (F/ATT/SIM/SS)
    const long long sC448 = 114688;   // 256*448
    const long long sH = 163840;      // 256*640

    zero_pool<<<400, 256, 0, stream>>>(POOL);
    make_mask<<<NB, 256, 0, stream>>>(x1, M1f);
    make_mask<<<NB, 256, 0, stream>>>(x2, M2f);
    prep_w<<<(256 * 320) / 256, 256, 0, stream>>>(Wi, 300, 200, WiT, 320, 256 * 320, 300, 320);
    prep_w<<<(256 * 256) / 256, 256, 0, stream>>>(Wa, 200, 200, WaT, 256, 256 * 256, 200, 256);
    prep_w<<<(256 * 640) / 256, 256, 0, stream>>>(Wp, 600, 200, WpT, 640, 256 * 640, 300, 320);
    prep_w<<<(512 * 448) / 256, 256, 0, stream>>>(Wc, 400, 400, WcT, 448, 512 * 448, 400, 448);

    // ---- stage A per side ------------------------------------------------
    for (int s = 0; s < 2; ++s) {
        const int* xs = s ? x2 : x1;
        u16* CMP = s ? CMP2 : CMP1;
        gather_norm<<<8192, 256, 0, stream>>>(xs, emb, H);
        // f = relu(e @ Wi + bi) -> F
        gemm<0, true, true, false, false, false><<<dim3(1, 256, 1), 512, 0, stream>>>(
            H, 640, 0, WiT, 320, 0, F, 256, 0, bi, 200,
            nullptr, nullptr, nullptr, 0, nullptr, 320, 0, 256);
        // att = f @ f^T (batched) -> SIM
        gemm<0, false, false, false, false, true><<<dim3(1, 2, NB), 512, 0, stream>>>(
            F, 256, sL, F, 256, sL, SIM, 256, sL, nullptr, 0,
            nullptr, nullptr, nullptr, 0, nullptr, 256, 0, 256);
        row_softmax<true><<<32768, 256, 0, stream>>>(SIM, b_dist);
        // xp = softmax(att) @ e -> H cols 320:640
        gemm<1, false, false, false, false, true><<<dim3(2, 2, NB), 512, 0, stream>>>(
            SIM, 256, sL, H, 640, sH, H + 320, 640, sH, nullptr, 0,
            nullptr, nullptr, nullptr, 0, nullptr, 256, 320, 320);
        // P = h @ Wp + bp -> CMP cols 0:256
        gemm<0, true, false, false, false, false><<<dim3(1, 256, 1), 512, 0, stream>>>(
            H, 640, 0, WpT, 640, 0, CMP, 448, 0, bp, 200,
            nullptr, nullptr, nullptr, 0, nullptr, 640, 0, 256);
    }

    // ---- cross attention ---------------------------------------------------
    // a1 = relu(P1 @ Wa + ba) -> F ; a2 -> ATT
    gemm<0, true, true, false, false, false><<<dim3(1, 256, 1), 512, 0, stream>>>(
        CMP1, 448, 0, WaT, 256, 0, F, 256, 0, ba, 200,
        nullptr, nullptr, nullptr, 0, nullptr, 256, 0, 256);
    gemm<0, true, true, false, false, false><<<dim3(1, 256, 1), 512, 0, stream>>>(
        CMP2, 448, 0, WaT, 256, 0, ATT, 256, 0, ba, 200,
        nullptr, nullptr, nullptr, 0, nullptr, 256, 0, 256);
    // sim = (a1 @ a2^T) * m1 x m2 -> SIM ; sim^T = (a2 @ a1^T) * m2 x m1 -> SS
    gemm<0, false, false, true, false, true><<<dim3(1, 2, NB), 512, 0, stream>>>(
        F, 256, sL, ATT, 256, sL, SIM, 256, sL, nullptr, 0,
        M1f, M2f, nullptr, 0, nullptr, 256, 0, 256);
    gemm<0, false, false, true, false, true><<<dim3(1, 2, NB), 512, 0, stream>>>(
        ATT, 256, sL, F, 256, sL, SS, 256, sL, nullptr, 0,
        M2f, M1f, nullptr, 0, nullptr, 256, 0, 256);
    row_softmax<false><<<32768, 256, 0, stream>>>(SIM, nullptr);
    row_softmax<false><<<32768, 256, 0, stream>>>(SS, nullptr);
    // beta = softmax(sim) @ P2 -> CMP1 cols 200:448 (cols>=400 become 0)
    gemm<1, false, false, false, false, true><<<dim3(1, 2, NB), 512, 0, stream>>>(
        SIM, 256, sL, CMP2, 448, sC448, CMP1 + 200, 448, sC448, nullptr, 0,
        nullptr, nullptr, nullptr, 0, nullptr, 256, 200, 248);
    // alpha = softmax(sim^T) @ P1 -> CMP2 cols 200:448
    gemm<1, false, false, false, false, true><<<dim3(1, 2, NB), 512, 0, stream>>>(
        SS, 256, sL, CMP1, 448, sC448, CMP2 + 200, 448, sC448, nullptr, 0,
        nullptr, nullptr, nullptr, 0, nullptr, 256, 200, 248);

    // ---- fused compare + masked pool ---------------------------------------
    gemm<0, true, true, false, true, false><<<dim3(2, 256, 1), 512, 0, stream>>>(
        CMP1, 448, 0, WcT, 448, 0, nullptr, 0, 0, bc, 400,
        nullptr, nullptr, POOL, 0, M1f, 448, 0, 400);
    gemm<0, true, true, false, true, false><<<dim3(2, 256, 1), 512, 0, stream>>>(
        CMP2, 448, 0, WcT, 448, 0, nullptr, 0, 0, bc, 400,
        nullptr, nullptr, POOL, 400, M2f, 448, 0, 400);

    final_fc<<<NB, 256, 0, stream>>>(POOL, Wg, bg, out);
}

// Round 5
// 424.129 us; speedup vs baseline: 1.0037x; 1.0037x over previous
//
#include <hip/hip_runtime.h>
#include <math.h>

#define LSEQ 256
#define NB   128

typedef unsigned short u16;
typedef unsigned int   u32;
typedef __attribute__((ext_vector_type(8))) short bf16x8;  // 8 bf16 = 4 VGPR
typedef __attribute__((ext_vector_type(4))) float f32x4;

static __device__ __forceinline__ u16 f2bf(float x) {
    union { float f; u32 u; } v; v.f = x;
    const u32 r = v.u + 0x7fffu + ((v.u >> 16) & 1u);   // RNE
    return (u16)(r >> 16);
}
static __device__ __forceinline__ float bf2f(u16 u) {
    union { u32 i; float f; } v; v.i = ((u32)u) << 16; return v.f;
}
// async global->LDS, 16B per lane, dest = wave-uniform base + lane*16
static __device__ __forceinline__ void glds16(const u16* src, u16* dst) {
    __builtin_amdgcn_global_load_lds(
        (const __attribute__((address_space(1))) u32*)src,
        (__attribute__((address_space(3))) u32*)dst, 16, 0, 0);
}

// ---------------------------------------------------------------------------
// bf16 MFMA GEMM. Block = 128 rows x 256 cols, 512 threads = 8 waves (2x4),
// wave tile 64x64 (4x4 fragments of 16x16x32). BK=64.
// A: bf16 row-major MxK (lda, K mult of 64, padded buffers). glds-staged.
// B: BMODE 0 -> bf16 [N][K] (TB), glds-staged. BMODE 1 -> bf16 [K][N],
//    reg-transpose staged, cols >= Bn read as 0.
// LDS: linear rows of 128B, 8 slots of 16B, XOR-swizzle slot ^= (row&7)
// applied on BOTH stage-source and read (involution, rule #21).
// Epilogue: bias (gc<Nbias), relu, mask (batched), or fused masked row-pool.
// ---------------------------------------------------------------------------
template<int BMODE, bool BIAS, bool RELU, bool MASKE, bool POOLE, bool BATCHED>
__global__ __launch_bounds__(512)
void gemm(const u16* __restrict__ A, int lda, long long sA,
          const u16* __restrict__ B, int ldb, long long sB,
          u16* __restrict__ C, int ldc, long long sC,
          const float* __restrict__ bias, int Nbias,
          const float* __restrict__ m1, const float* __restrict__ m2,
          float* __restrict__ pool, int poolOff, const float* __restrict__ pmask,
          int K, int Bn, int Nwrite)
{
    __shared__ u16 As[128 * 64];   // 16 KB
    __shared__ u16 Bs[256 * 64];   // 32 KB

    const int bz = BATCHED ? blockIdx.z : 0;
    const u16* Ab = A + (long long)bz * sA;
    const u16* Bb = B + (long long)bz * sB;
    const int m0 = blockIdx.y * 128;
    const int n0 = blockIdx.x * 256;
    const int t = threadIdx.x;
    const int lane = t & 63;
    const int w = t >> 6;          // 0..7
    const int wm = w >> 2;         // 0..1
    const int wn = w & 3;          // 0..3
    const int lr = lane & 15;
    const int lg = lane >> 4;      // 0..3

    f32x4 acc[4][4] = {};

    for (int k0 = 0; k0 < K; k0 += 64) {
        // ---- stage A: 16 KB = 16 chunks of 1KB; wave w -> chunks 2w,2w+1
#pragma unroll
        for (int i = 0; i < 2; ++i) {
            const int ch = w * 2 + i;
            const int row = (ch << 3) + (lane >> 3);
            const int slot = (lane & 7) ^ (row & 7);
            glds16(Ab + (long long)(m0 + row) * lda + k0 + (slot << 3),
                   &As[ch << 9]);
        }
        // ---- stage B
        if (BMODE == 0) {
#pragma unroll
            for (int i = 0; i < 4; ++i) {
                const int ch = w * 4 + i;
                const int row = (ch << 3) + (lane >> 3);
                const int slot = (lane & 7) ^ (row & 7);
                glds16(Bb + (long long)(n0 + row) * ldb + k0 + (slot << 3),
                       &Bs[ch << 9]);
            }
        } else {
            // B is [K][N]: thread covers 8k x 4n, transpose in regs
            const int n4 = (t & 63) << 2;    // 0..252
            const int k8 = w << 3;           // 0..56
            union { uint2 q2[8]; u16 s[32]; } uq;
#pragma unroll
            for (int i = 0; i < 8; ++i)
                uq.q2[i] = *reinterpret_cast<const uint2*>(
                    Bb + (long long)(k0 + k8 + i) * ldb + n0 + n4);
#pragma unroll
            for (int j = 0; j < 4; ++j) {
                u32 v0 = 0, v1 = 0, v2 = 0, v3 = 0;
                if (n0 + n4 + j < Bn) {
                    v0 = (u32)uq.s[j]      | ((u32)uq.s[4 + j]  << 16);
                    v1 = (u32)uq.s[8 + j]  | ((u32)uq.s[12 + j] << 16);
                    v2 = (u32)uq.s[16 + j] | ((u32)uq.s[20 + j] << 16);
                    v3 = (u32)uq.s[24 + j] | ((u32)uq.s[28 + j] << 16);
                }
                const int row = n4 + j;
                const int slot = w ^ (row & 7);
                *reinterpret_cast<uint4*>(&Bs[row * 64 + (slot << 3)]) =
                    make_uint4(v0, v1, v2, v3);
            }
        }
        __syncthreads();

        // ---- fragments + MFMA (2 k-halves of 32)
#pragma unroll
        for (int kk = 0; kk < 2; ++kk) {
            bf16x8 af[4], bf[4];
#pragma unroll
            for (int mi = 0; mi < 4; ++mi) {
                const int row = wm * 64 + mi * 16 + lr;
                const int slot = ((kk << 2) + lg) ^ (row & 7);
                af[mi] = *reinterpret_cast<const bf16x8*>(&As[row * 64 + (slot << 3)]);
            }
#pragma unroll
            for (int ni = 0; ni < 4; ++ni) {
                const int row = wn * 64 + ni * 16 + lr;
                const int slot = ((kk << 2) + lg) ^ (row & 7);
                bf[ni] = *reinterpret_cast<const bf16x8*>(&Bs[row * 64 + (slot << 3)]);
            }
#pragma unroll
            for (int mi = 0; mi < 4; ++mi)
#pragma unroll
                for (int ni = 0; ni < 4; ++ni)
                    acc[mi][ni] = __builtin_amdgcn_mfma_f32_16x16x32_bf16(
                        af[mi], bf[ni], acc[mi][ni], 0, 0, 0);
        }
        __syncthreads();
    }

    const int rbase = lg << 2;
    if (!POOLE) {
        u16* Cb = C + (long long)bz * sC;
        float m1v[4][4];
        if (MASKE) {
#pragma unroll
            for (int mi = 0; mi < 4; ++mi)
#pragma unroll
                for (int r = 0; r < 4; ++r)
                    m1v[mi][r] = m1[bz * 256 + m0 + wm * 64 + mi * 16 + rbase + r];
        }
#pragma unroll
        for (int ni = 0; ni < 4; ++ni) {
            const int gc = n0 + wn * 64 + ni * 16 + lr;
            if (gc >= Nwrite) continue;
            float bcv = 0.f;
            if (BIAS) bcv = (gc < Nbias) ? bias[gc] : 0.f;
            float m2v = 0.f;
            if (MASKE) m2v = m2[bz * 256 + gc];
#pragma unroll
            for (int mi = 0; mi < 4; ++mi) {
#pragma unroll
                for (int r = 0; r < 4; ++r) {
                    const long long gr = m0 + wm * 64 + mi * 16 + rbase + r;
                    float x = acc[mi][ni][r];
                    if (BIAS) x += bcv;
                    if (RELU) x = fmaxf(x, 0.f);
                    if (MASKE) x *= m1v[mi][r] * m2v;
                    Cb[gr * ldc + gc] = f2bf(x);
                }
            }
        }
    } else {
        // fused compare epilogue: pooled[b][poolOff+gc] += relu(acc+bc)*mask[row]
        __syncthreads();
        float* pool_s = reinterpret_cast<float*>(As);
        for (int i = t; i < 256; i += 512) pool_s[i] = 0.f;
        __syncthreads();
        const int b = m0 >> 8;
        const float* mk = pmask + b * 256 + (m0 & 255);
        float mrow[4][4];
#pragma unroll
        for (int mi = 0; mi < 4; ++mi)
#pragma unroll
            for (int r = 0; r < 4; ++r)
                mrow[mi][r] = mk[wm * 64 + mi * 16 + rbase + r];
#pragma unroll
        for (int ni = 0; ni < 4; ++ni) {
            const int lc = wn * 64 + ni * 16 + lr;
            const int gc = n0 + lc;
            const float bcv = (BIAS && gc < Nbias) ? bias[gc] : 0.f;
            float cs = 0.f;
#pragma unroll
            for (int mi = 0; mi < 4; ++mi)
#pragma unroll
                for (int r = 0; r < 4; ++r)
                    cs += fmaxf(acc[mi][ni][r] + bcv, 0.f) * mrow[mi][r];
            cs += __shfl_xor(cs, 16, 64);
            cs += __shfl_xor(cs, 32, 64);
            if (lg == 0) atomicAdd(&pool_s[lc], cs);
        }
        __syncthreads();
        for (int i = t; i < 256; i += 512) {
            const int gc = n0 + i;
            if (gc < Nwrite) atomicAdd(&pool[b * 800 + poolOff + gc], pool_s[i]);
        }
    }
}

// ---------------------------------------------------------------------------
// weight prep: dst[n][k] (bf16, [dstRows][dstCols]) = src[srcRow(k)][n] or 0.
// srcRow(k): k<seg1 -> k ; seg2start<=k<seg2start+(srcRows-seg1) -> seg1+(k-seg2start)
// ---------------------------------------------------------------------------
__global__ __launch_bounds__(256)
void prep_w(const float* __restrict__ src, int srcRows, int srcCols,
            u16* __restrict__ dst, int dstCols, int dstTotal,
            int seg1, int seg2start)
{
    const int idx = blockIdx.x * 256 + threadIdx.x;
    if (idx >= dstTotal) return;
    const int n = idx / dstCols, k = idx - n * dstCols;
    int sr = -1;
    if (k < seg1) sr = k;
    else if (k >= seg2start && (k - seg2start) < (srcRows - seg1)) sr = seg1 + (k - seg2start);
    u16 v = 0;
    if (n < srcCols && sr >= 0) v = f2bf(src[(long long)sr * srcCols + n]);
    dst[idx] = v;
}

__global__ __launch_bounds__(256)
void zero_pool(float* __restrict__ p)
{
    p[blockIdx.x * 256 + threadIdx.x] = 0.f;
}

// mask[b][l] = (l < count_nonzero(x[b,:])) ? 1 : 0
__global__ __launch_bounds__(256)
void make_mask(const int* __restrict__ x, float* __restrict__ mask)
{
    const int b = blockIdx.x;
    const int t = threadIdx.x;
    int nz = (x[b * LSEQ + t] != 0) ? 1 : 0;
#pragma unroll
    for (int o = 32; o; o >>= 1) nz += __shfl_xor(nz, o, 64);
    __shared__ int red[4];
    if ((t & 63) == 0) red[t >> 6] = nz;
    __syncthreads();
    const int size = red[0] + red[1] + red[2] + red[3];
    mask[b * LSEQ + t] = (t < size) ? 1.0f : 0.0f;
}

// gather + L2-normalize -> H[row][0:320] bf16 (cols 300-319 zero), pitch 640
__global__ __launch_bounds__(256)
void gather_norm(const int* __restrict__ x, const float* __restrict__ emb,
                 u16* __restrict__ h)
{
    const int t = threadIdx.x;
    const int lane = t & 63;
    const long long row = (long long)blockIdx.x * 4 + (t >> 6);
    const int tok = x[row];
    const float* er = emb + (long long)tok * 300;
    float vals[5];
    float ss = 0.f;
#pragma unroll
    for (int i = 0; i < 5; ++i) {
        const int c = lane + i * 64;
        const float v = (c < 300) ? er[c] : 0.f;
        vals[i] = v;
        ss = fmaf(v, v, ss);
    }
#pragma unroll
    for (int o = 32; o; o >>= 1) ss += __shfl_xor(ss, o, 64);
    const float inv = 1.0f / sqrtf(ss);
    u16* out = h + row * 640;
#pragma unroll
    for (int i = 0; i < 5; ++i) {
        const int c = lane + i * 64;
        out[c] = f2bf(vals[i] * inv);
    }
}

// in-place row softmax over 256 (bf16), optional distance bias
template<bool DBIAS>
__global__ __launch_bounds__(256)
void row_softmax(u16* __restrict__ buf, const float* __restrict__ b_dist)
{
    const long long row = blockIdx.x;
    const int i = (int)(row & 255);
    const int t = threadIdx.x;
    float v = bf2f(buf[row * 256 + t]);
    if (DBIAS) {
        const int d = (i > t) ? (i - t) : (t - i);
        if (d >= 10) v += b_dist[0];
    }
    float m = v;
#pragma unroll
    for (int o = 32; o; o >>= 1) m = fmaxf(m, __shfl_xor(m, o, 64));
    __shared__ float redm[4];
    if ((t & 63) == 0) redm[t >> 6] = m;
    __syncthreads();
    m = fmaxf(fmaxf(redm[0], redm[1]), fmaxf(redm[2], redm[3]));
    const float e = expf(v - m);
    float s = e;
#pragma unroll
    for (int o = 32; o; o >>= 1) s += __shfl_xor(s, o, 64);
    __shared__ float reds[4];
    if ((t & 63) == 0) reds[t >> 6] = s;
    __syncthreads();
    s = reds[0] + reds[1] + reds[2] + reds[3];
    buf[row * 256 + t] = f2bf(e / s);
}

__global__ __launch_bounds__(256)
void final_fc(const float* __restrict__ pooled, const float* __restrict__ Wg,
              const float* __restrict__ bg, float* __restrict__ out)
{
    const int b = blockIdx.x;
    const int t = threadIdx.x;
    float a0 = 0.f, a1 = 0.f, a2 = 0.f;
    for (int k = t; k < 800; k += 256) {
        const float p = pooled[(long long)b * 800 + k];
        a0 = fmaf(p, Wg[k * 3 + 0], a0);
        a1 = fmaf(p, Wg[k * 3 + 1], a1);
        a2 = fmaf(p, Wg[k * 3 + 2], a2);
    }
#pragma unroll
    for (int o = 32; o; o >>= 1) {
        a0 += __shfl_xor(a0, o, 64);
        a1 += __shfl_xor(a1, o, 64);
        a2 += __shfl_xor(a2, o, 64);
    }
    __shared__ float r0[4], r1[4], r2[4];
    if ((t & 63) == 0) { r0[t >> 6] = a0; r1[t >> 6] = a1; r2[t >> 6] = a2; }
    __syncthreads();
    if (t == 0) {
        out[b * 3 + 0] = r0[0] + r0[1] + r0[2] + r0[3] + bg[0];
        out[b * 3 + 1] = r1[0] + r1[1] + r1[2] + r1[3] + bg[1];
        out[b * 3 + 2] = r2[0] + r2[1] + r2[2] + r2[3] + bg[2];
    }
}

// ---------------------------------------------------------------------------
extern "C" void kernel_launch(void* const* d_in, const int* in_sizes, int n_in,
                              void* d_out, int out_size, void* d_ws, size_t ws_size,
                              hipStream_t stream)
{
    (void)in_sizes; (void)n_in; (void)out_size; (void)ws_size;

    const int*   x1     = (const int*)  d_in[0];
    const int*   x2     = (const int*)  d_in[1];
    const float* emb    = (const float*)d_in[2];
    const float* Wi     = (const float*)d_in[3];
    const float* bi     = (const float*)d_in[4];
    const float* b_dist = (const float*)d_in[5];
    const float* Wp     = (const float*)d_in[6];
    const float* bp     = (const float*)d_in[7];
    const float* Wa     = (const float*)d_in[8];
    const float* ba     = (const float*)d_in[9];
    const float* Wc     = (const float*)d_in[10];
    const float* bc     = (const float*)d_in[11];
    const float* Wg     = (const float*)d_in[12];
    const float* bg     = (const float*)d_in[13];
    float* out = (float*)d_out;

    // ---- workspace (bf16 unless noted), all bases 16B-aligned -----------
    u16* wsu  = (u16*)d_ws;
    u16* H    = wsu;               // [32768][640]: e(0:300)|0|xp(320:620)|0
    u16* CMP1 = wsu + 20971520;    // [32768][448]: P1(0:200)|beta(200:400)|0
    u16* CMP2 = wsu + 35651584;    // [32768][448]: P2 | alpha | 0
    u16* F    = wsu + 50331648;    // [32768][256]: f / a1
    u16* ATT  = wsu + 58720256;    // [32768][256]: a2
    u16* SIM  = wsu + 67108864;    // [128][256][256]
    u16* SS   = wsu + 75497472;    // [128][256][256]
    u16* WiT  = wsu + 83886080;    // [256][320]
    u16* WaT  = wsu + 83968000;    // [256][256]
    u16* WpT  = wsu + 84033536;    // [256][640]
    u16* WcT  = wsu + 84197376;    // [512][448]
    float* fb = (float*)(wsu + 84426752);
    float* POOL = fb;              // [128][800]
    float* M1f  = fb + 102400;     // [128][256]
    float* M2f  = fb + 135168;

    const long long sL = 65536;    // 256*256 per-batch stride (F/ATT/SIM/SS)
    const long long sC448 = 114688;   // 256*448
    const long long sH = 163840;      // 256*640

    zero_pool<<<400, 256, 0, stream>>>(POOL);
    make_mask<<<NB, 256, 0, stream>>>(x1, M1f);
    make_mask<<<NB, 256, 0, stream>>>(x2, M2f);
    prep_w<<<(256 * 320) / 256, 256, 0, stream>>>(Wi, 300, 200, WiT, 320, 256 * 320, 300, 320);
    prep_w<<<(256 * 256) / 256, 256, 0, stream>>>(Wa, 200, 200, WaT, 256, 256 * 256, 200, 256);
    prep_w<<<(256 * 640) / 256, 256, 0, stream>>>(Wp, 600, 200, WpT, 640, 256 * 640, 300, 320);
    prep_w<<<(512 * 448) / 256, 256, 0, stream>>>(Wc, 400, 400, WcT, 448, 512 * 448, 400, 448);

    // ---- stage A per side ------------------------------------------------
    for (int s = 0; s < 2; ++s) {
        const int* xs = s ? x2 : x1;
        u16* CMP = s ? CMP2 : CMP1;
        gather_norm<<<8192, 256, 0, stream>>>(xs, emb, H);
        // f = relu(e @ Wi + bi) -> F
        gemm<0, true, true, false, false, false><<<dim3(1, 256, 1), 512, 0, stream>>>(
            H, 640, 0, WiT, 320, 0, F, 256, 0, bi, 200,
            nullptr, nullptr, nullptr, 0, nullptr, 320, 0, 256);
        // att = f @ f^T (batched) -> SIM
        gemm<0, false, false, false, false, true><<<dim3(1, 2, NB), 512, 0, stream>>>(
            F, 256, sL, F, 256, sL, SIM, 256, sL, nullptr, 0,
            nullptr, nullptr, nullptr, 0, nullptr, 256, 0, 256);
        row_softmax<true><<<32768, 256, 0, stream>>>(SIM, b_dist);
        // xp = softmax(att) @ e -> H cols 320:640
        gemm<1, false, false, false, false, true><<<dim3(2, 2, NB), 512, 0, stream>>>(
            SIM, 256, sL, H, 640, sH, H + 320, 640, sH, nullptr, 0,
            nullptr, nullptr, nullptr, 0, nullptr, 256, 320, 320);
        // P = h @ Wp + bp -> CMP cols 0:256
        gemm<0, true, false, false, false, false><<<dim3(1, 256, 1), 512, 0, stream>>>(
            H, 640, 0, WpT, 640, 0, CMP, 448, 0, bp, 200,
            nullptr, nullptr, nullptr, 0, nullptr, 640, 0, 256);
    }

    // ---- cross attention ---------------------------------------------------
    // a1 = relu(P1 @ Wa + ba) -> F ; a2 -> ATT
    gemm<0, true, true, false, false, false><<<dim3(1, 256, 1), 512, 0, stream>>>(
        CMP1, 448, 0, WaT, 256, 0, F, 256, 0, ba, 200,
        nullptr, nullptr, nullptr, 0, nullptr, 256, 0, 256);
    gemm<0, true, true, false, false, false><<<dim3(1, 256, 1), 512, 0, stream>>>(
        CMP2, 448, 0, WaT, 256, 0, ATT, 256, 0, ba, 200,
        nullptr, nullptr, nullptr, 0, nullptr, 256, 0, 256);
    // sim = (a1 @ a2^T) * m1 x m2 -> SIM ; sim^T = (a2 @ a1^T) * m2 x m1 -> SS
    gemm<0, false, false, true, false, true><<<dim3(1, 2, NB), 512, 0, stream>>>(
        F, 256, sL, ATT, 256, sL, SIM, 256, sL, nullptr, 0,
        M1f, M2f, nullptr, 0, nullptr, 256, 0, 256);
    gemm<0, false, false, true, false, true><<<dim3(1, 2, NB), 512, 0, stream>>>(
        ATT, 256, sL, F, 256, sL, SS, 256, sL, nullptr, 0,
        M2f, M1f, nullptr, 0, nullptr, 256, 0, 256);
    row_softmax<false><<<32768, 256, 0, stream>>>(SIM, nullptr);
    row_softmax<false><<<32768, 256, 0, stream>>>(SS, nullptr);
    // beta = softmax(sim) @ P2 -> CMP1 cols 200:448 (cols>=400 become 0)
    gemm<1, false, false, false, false, true><<<dim3(1, 2, NB), 512, 0, stream>>>(
        SIM, 256, sL, CMP2, 448, sC448, CMP1 + 200, 448, sC448, nullptr, 0,
        nullptr, nullptr, nullptr, 0, nullptr, 256, 200, 248);
    // alpha = softmax(sim^T) @ P1 -> CMP2 cols 200:448
    gemm<1, false, false, false, false, true><<<dim3(1, 2, NB), 512, 0, stream>>>(
        SS, 256, sL, CMP1, 448, sC448, CMP2 + 200, 448, sC448, nullptr, 0,
        nullptr, nullptr, nullptr, 0, nullptr, 256, 200, 248);

    // ---- fused compare + masked pool ---------------------------------------
    gemm<0, true, true, false, true, false><<<dim3(2, 256, 1), 512, 0, stream>>>(
        CMP1, 448, 0, WcT, 448, 0, nullptr, 0, 0, bc, 400,
        nullptr, nullptr, POOL, 0, M1f, 448, 0, 400);
    gemm<0, true, true, false, true, false><<<dim3(2, 256, 1), 512, 0, stream>>>(
        CMP2, 448, 0, WcT, 448, 0, nullptr, 0, 0, bc, 400,
        nullptr, nullptr, POOL, 400, M2f, 448, 0, 400);

    final_fc<<<NB, 256, 0, stream>>>(POOL, Wg, bg, out);
}

// Round 6
// 423.993 us; speedup vs baseline: 1.0040x; 1.0003x over previous
//
#include <hip/hip_runtime.h>
#include <math.h>

#define LSEQ 256
#define NB   128

typedef unsigned short u16;
typedef unsigned int   u32;
typedef __attribute__((ext_vector_type(8))) short bf16x8;  // 8 bf16 = 4 VGPR
typedef __attribute__((ext_vector_type(4))) float f32x4;

static __device__ __forceinline__ u16 f2bf(float x) {
    union { float f; u32 u; } v; v.f = x;
    const u32 r = v.u + 0x7fffu + ((v.u >> 16) & 1u);   // RNE
    return (u16)(r >> 16);
}
static __device__ __forceinline__ float bf2f(u16 u) {
    union { u32 i; float f; } v; v.i = ((u32)u) << 16; return v.f;
}
// async global->LDS, 16B per lane, dest = wave-uniform base + lane*16
static __device__ __forceinline__ void glds16(const u16* src, u16* dst) {
    __builtin_amdgcn_global_load_lds(
        (const __attribute__((address_space(1))) u32*)src,
        (__attribute__((address_space(3))) u32*)dst, 16, 0, 0);
}

// ---------------------------------------------------------------------------
// bf16 MFMA GEMM. Block = 128 rows x 256 cols, 512 threads = 8 waves (2x4),
// wave tile 64x64 (4x4 fragments of 16x16x32). BK=64.
// A: bf16 row-major MxK (lda, K mult of 64, padded buffers). glds-staged.
// B: BMODE 0 -> bf16 [N][K] (TB), glds-staged. BMODE 1 -> bf16 [K][N],
//    reg-transpose staged, cols >= Bn read as 0.
// LDS: linear rows of 128B, 8 slots of 16B, XOR-swizzle slot ^= (row&7)
// applied on BOTH stage-source and read (involution, rule #21).
// Epilogue: bias (gc<Nbias), relu, mask (batched), or fused masked row-pool.
// ---------------------------------------------------------------------------
template<int BMODE, bool BIAS, bool RELU, bool MASKE, bool POOLE, bool BATCHED>
__global__ __launch_bounds__(512)
void gemm(const u16* __restrict__ A, int lda, long long sA,
          const u16* __restrict__ B, int ldb, long long sB,
          u16* __restrict__ C, int ldc, long long sC,
          const float* __restrict__ bias, int Nbias,
          const float* __restrict__ m1, const float* __restrict__ m2,
          float* __restrict__ pool, int poolOff, const float* __restrict__ pmask,
          int K, int Bn, int Nwrite)
{
    __shared__ u16 As[128 * 64];   // 16 KB
    __shared__ u16 Bs[256 * 64];   // 32 KB

    const int bz = BATCHED ? blockIdx.z : 0;
    const u16* Ab = A + (long long)bz * sA;
    const u16* Bb = B + (long long)bz * sB;
    const int m0 = blockIdx.y * 128;
    const int n0 = blockIdx.x * 256;
    const int t = threadIdx.x;
    const int lane = t & 63;
    const int w = t >> 6;          // 0..7
    const int wm = w >> 2;         // 0..1
    const int wn = w & 3;          // 0..3
    const int lr = lane & 15;
    const int lg = lane >> 4;      // 0..3

    f32x4 acc[4][4] = {};

    for (int k0 = 0; k0 < K; k0 += 64) {
        // ---- stage A: 16 KB = 16 chunks of 1KB; wave w -> chunks 2w,2w+1
#pragma unroll
        for (int i = 0; i < 2; ++i) {
            const int ch = w * 2 + i;
            const int row = (ch << 3) + (lane >> 3);
            const int slot = (lane & 7) ^ (row & 7);
            glds16(Ab + (long long)(m0 + row) * lda + k0 + (slot << 3),
                   &As[ch << 9]);
        }
        // ---- stage B
        if (BMODE == 0) {
#pragma unroll
            for (int i = 0; i < 4; ++i) {
                const int ch = w * 4 + i;
                const int row = (ch << 3) + (lane >> 3);
                const int slot = (lane & 7) ^ (row & 7);
                glds16(Bb + (long long)(n0 + row) * ldb + k0 + (slot << 3),
                       &Bs[ch << 9]);
            }
        } else {
            // B is [K][N]: thread covers 8k x 4n, transpose in regs
            const int n4 = (t & 63) << 2;    // 0..252
            const int k8 = w << 3;           // 0..56
            union { uint2 q2[8]; u16 s[32]; } uq;
#pragma unroll
            for (int i = 0; i < 8; ++i)
                uq.q2[i] = *reinterpret_cast<const uint2*>(
                    Bb + (long long)(k0 + k8 + i) * ldb + n0 + n4);
#pragma unroll
            for (int j = 0; j < 4; ++j) {
                u32 v0 = 0, v1 = 0, v2 = 0, v3 = 0;
                if (n0 + n4 + j < Bn) {
                    v0 = (u32)uq.s[j]      | ((u32)uq.s[4 + j]  << 16);
                    v1 = (u32)uq.s[8 + j]  | ((u32)uq.s[12 + j] << 16);
                    v2 = (u32)uq.s[16 + j] | ((u32)uq.s[20 + j] << 16);
                    v3 = (u32)uq.s[24 + j] | ((u32)uq.s[28 + j] << 16);
                }
                const int row = n4 + j;
                const int slot = w ^ (row & 7);
                *reinterpret_cast<uint4*>(&Bs[row * 64 + (slot << 3)]) =
                    make_uint4(v0, v1, v2, v3);
            }
        }
        __syncthreads();

        // ---- fragments + MFMA (2 k-halves of 32)
#pragma unroll
        for (int kk = 0; kk < 2; ++kk) {
            bf16x8 af[4], bf[4];
#pragma unroll
            for (int mi = 0; mi < 4; ++mi) {
                const int row = wm * 64 + mi * 16 + lr;
                const int slot = ((kk << 2) + lg) ^ (row & 7);
                af[mi] = *reinterpret_cast<const bf16x8*>(&As[row * 64 + (slot << 3)]);
            }
#pragma unroll
            for (int ni = 0; ni < 4; ++ni) {
                const int row = wn * 64 + ni * 16 + lr;
                const int slot = ((kk << 2) + lg) ^ (row & 7);
                bf[ni] = *reinterpret_cast<const bf16x8*>(&Bs[row * 64 + (slot << 3)]);
            }
#pragma unroll
            for (int mi = 0; mi < 4; ++mi)
#pragma unroll
                for (int ni = 0; ni < 4; ++ni)
                    acc[mi][ni] = __builtin_amdgcn_mfma_f32_16x16x32_bf16(
                        af[mi], bf[ni], acc[mi][ni], 0, 0, 0);
        }
        __syncthreads();
    }

    const int rbase = lg << 2;
    if (!POOLE) {
        u16* Cb = C + (long long)bz * sC;
        float m1v[4][4];
        if (MASKE) {
#pragma unroll
            for (int mi = 0; mi < 4; ++mi)
#pragma unroll
                for (int r = 0; r < 4; ++r)
                    m1v[mi][r] = m1[bz * 256 + m0 + wm * 64 + mi * 16 + rbase + r];
        }
#pragma unroll
        for (int ni = 0; ni < 4; ++ni) {
            const int gc = n0 + wn * 64 + ni * 16 + lr;
            if (gc >= Nwrite) continue;
            float bcv = 0.f;
            if (BIAS) bcv = (gc < Nbias) ? bias[gc] : 0.f;
            float m2v = 0.f;
            if (MASKE) m2v = m2[bz * 256 + gc];
#pragma unroll
            for (int mi = 0; mi < 4; ++mi) {
#pragma unroll
                for (int r = 0; r < 4; ++r) {
                    const long long gr = m0 + wm * 64 + mi * 16 + rbase + r;
                    float x = acc[mi][ni][r];
                    if (BIAS) x += bcv;
                    if (RELU) x = fmaxf(x, 0.f);
                    if (MASKE) x *= m1v[mi][r] * m2v;
                    Cb[gr * ldc + gc] = f2bf(x);
                }
            }
        }
    } else {
        // fused compare epilogue: pooled[b][poolOff+gc] += relu(acc+bc)*mask[row]
        __syncthreads();
        float* pool_s = reinterpret_cast<float*>(As);
        for (int i = t; i < 256; i += 512) pool_s[i] = 0.f;
        __syncthreads();
        const int b = m0 >> 8;
        const float* mk = pmask + b * 256 + (m0 & 255);
        float mrow[4][4];
#pragma unroll
        for (int mi = 0; mi < 4; ++mi)
#pragma unroll
            for (int r = 0; r < 4; ++r)
                mrow[mi][r] = mk[wm * 64 + mi * 16 + rbase + r];
#pragma unroll
        for (int ni = 0; ni < 4; ++ni) {
            const int lc = wn * 64 + ni * 16 + lr;
            const int gc = n0 + lc;
            const float bcv = (BIAS && gc < Nbias) ? bias[gc] : 0.f;
            float cs = 0.f;
#pragma unroll
            for (int mi = 0; mi < 4; ++mi)
#pragma unroll
                for (int r = 0; r < 4; ++r)
                    cs += fmaxf(acc[mi][ni][r] + bcv, 0.f) * mrow[mi][r];
            cs += __shfl_xor(cs, 16, 64);
            cs += __shfl_xor(cs, 32, 64);
            if (lg == 0) atomicAdd(&pool_s[lc], cs);
        }
        __syncthreads();
        for (int i = t; i < 256; i += 512) {
            const int gc = n0 + i;
            if (gc < Nwrite) atomicAdd(&pool[b * 800 + poolOff + gc], pool_s[i]);
        }
    }
}

// ---------------------------------------------------------------------------
// weight prep: dst[n][k] (bf16, [dstRows][dstCols]) = src[srcRow(k)][n] or 0.
// srcRow(k): k<seg1 -> k ; seg2start<=k<seg2start+(srcRows-seg1) -> seg1+(k-seg2start)
// ---------------------------------------------------------------------------
__global__ __launch_bounds__(256)
void prep_w(const float* __restrict__ src, int srcRows, int srcCols,
            u16* __restrict__ dst, int dstCols, int dstTotal,
            int seg1, int seg2start)
{
    const int idx = blockIdx.x * 256 + threadIdx.x;
    if (idx >= dstTotal) return;
    const int n = idx / dstCols, k = idx - n * dstCols;
    int sr = -1;
    if (k < seg1) sr = k;
    else if (k >= seg2start && (k - seg2start) < (srcRows - seg1)) sr = seg1 + (k - seg2start);
    u16 v = 0;
    if (n < srcCols && sr >= 0) v = f2bf(src[(long long)sr * srcCols + n]);
    dst[idx] = v;
}

__global__ __launch_bounds__(256)
void zero_pool(float* __restrict__ p)
{
    p[blockIdx.x * 256 + threadIdx.x] = 0.f;
}

// mask[b][l] = (l < count_nonzero(x[b,:])) ? 1 : 0
__global__ __launch_bounds__(256)
void make_mask(const int* __restrict__ x, float* __restrict__ mask)
{
    const int b = blockIdx.x;
    const int t = threadIdx.x;
    int nz = (x[b * LSEQ + t] != 0) ? 1 : 0;
#pragma unroll
    for (int o = 32; o; o >>= 1) nz += __shfl_xor(nz, o, 64);
    __shared__ int red[4];
    if ((t & 63) == 0) red[t >> 6] = nz;
    __syncthreads();
    const int size = red[0] + red[1] + red[2] + red[3];
    mask[b * LSEQ + t] = (t < size) ? 1.0f : 0.0f;
}

// gather + L2-normalize -> H[row][0:320] bf16 (cols 300-319 zero), pitch 640
__global__ __launch_bounds__(256)
void gather_norm(const int* __restrict__ x, const float* __restrict__ emb,
                 u16* __restrict__ h)
{
    const int t = threadIdx.x;
    const int lane = t & 63;
    const long long row = (long long)blockIdx.x * 4 + (t >> 6);
    const int tok = x[row];
    const float* er = emb + (long long)tok * 300;
    float vals[5];
    float ss = 0.f;
#pragma unroll
    for (int i = 0; i < 5; ++i) {
        const int c = lane + i * 64;
        const float v = (c < 300) ? er[c] : 0.f;
        vals[i] = v;
        ss = fmaf(v, v, ss);
    }
#pragma unroll
    for (int o = 32; o; o >>= 1) ss += __shfl_xor(ss, o, 64);
    const float inv = 1.0f / sqrtf(ss);
    u16* out = h + row * 640;
#pragma unroll
    for (int i = 0; i < 5; ++i) {
        const int c = lane + i * 64;
        out[c] = f2bf(vals[i] * inv);
    }
}

// in-place row softmax over 256 (bf16), optional distance bias
template<bool DBIAS>
__global__ __launch_bounds__(256)
void row_softmax(u16* __restrict__ buf, const float* __restrict__ b_dist)
{
    const long long row = blockIdx.x;
    const int i = (int)(row & 255);
    const int t = threadIdx.x;
    float v = bf2f(buf[row * 256 + t]);
    if (DBIAS) {
        const int d = (i > t) ? (i - t) : (t - i);
        if (d >= 10) v += b_dist[0];
    }
    float m = v;
#pragma unroll
    for (int o = 32; o; o >>= 1) m = fmaxf(m, __shfl_xor(m, o, 64));
    __shared__ float redm[4];
    if ((t & 63) == 0) redm[t >> 6] = m;
    __syncthreads();
    m = fmaxf(fmaxf(redm[0], redm[1]), fmaxf(redm[2], redm[3]));
    const float e = expf(v - m);
    float s = e;
#pragma unroll
    for (int o = 32; o; o >>= 1) s += __shfl_xor(s, o, 64);
    __shared__ float reds[4];
    if ((t & 63) == 0) reds[t >> 6] = s;
    __syncthreads();
    s = reds[0] + reds[1] + reds[2] + reds[3];
    buf[row * 256 + t] = f2bf(e / s);
}

__global__ __launch_bounds__(256)
void final_fc(const float* __restrict__ pooled, const float* __restrict__ Wg,
              const float* __restrict__ bg, float* __restrict__ out)
{
    const int b = blockIdx.x;
    const int t = threadIdx.x;
    float a0 = 0.f, a1 = 0.f, a2 = 0.f;
    for (int k = t; k < 800; k += 256) {
        const float p = pooled[(long long)b * 800 + k];
        a0 = fmaf(p, Wg[k * 3 + 0], a0);
        a1 = fmaf(p, Wg[k * 3 + 1], a1);
        a2 = fmaf(p, Wg[k * 3 + 2], a2);
    }
#pragma unroll
    for (int o = 32; o; o >>= 1) {
        a0 += __shfl_xor(a0, o, 64);
        a1 += __shfl_xor(a1, o, 64);
        a2 += __shfl_xor(a2, o, 64);
    }
    __shared__ float r0[4], r1[4], r2[4];
    if ((t & 63) == 0) { r0[t >> 6] = a0; r1[t >> 6] = a1; r2[t >> 6] = a2; }
    __syncthreads();
    if (t == 0) {
        out[b * 3 + 0] = r0[0] + r0[1] + r0[2] + r0[3] + bg[0];
        out[b * 3 + 1] = r1[0] + r1[1] + r1[2] + r1[3] + bg[1];
        out[b * 3 + 2] = r2[0] + r2[1] + r2[2] + r2[3] + bg[2];
    }
}

// ---------------------------------------------------------------------------
extern "C" void kernel_launch(void* const* d_in, const int* in_sizes, int n_in,
                              void* d_out, int out_size, void* d_ws, size_t ws_size,
                              hipStream_t stream)
{
    (void)in_sizes; (void)n_in; (void)out_size; (void)ws_size;

    const int*   x1     = (const int*)  d_in[0];
    const int*   x2     = (const int*)  d_in[1];
    const float* emb    = (const float*)d_in[2];
    const float* Wi     = (const float*)d_in[3];
    const float* bi     = (const float*)d_in[4];
    const float* b_dist = (const float*)d_in[5];
    const float* Wp     = (const float*)d_in[6];
    const float* bp     = (const float*)d_in[7];
    const float* Wa     = (const float*)d_in[8];
    const float* ba     = (const float*)d_in[9];
    const float* Wc     = (const float*)d_in[10];
    const float* bc     = (const float*)d_in[11];
    const float* Wg     = (const float*)d_in[12];
    const float* bg     = (const float*)d_in[13];
    float* out = (float*)d_out;

    // ---- workspace (bf16 unless noted), all bases 16B-aligned -----------
    u16* wsu  = (u16*)d_ws;
    u16* H    = wsu;               // [32768][640]: e(0:300)|0|xp(320:620)|0
    u16* CMP1 = wsu + 20971520;    // [32768][448]: P1(0:200)|beta(200:400)|0
    u16* CMP2 = wsu + 35651584;    // [32768][448]: P2 | alpha | 0
    u16* F    = wsu + 50331648;    // [32768][256]: f / a1
    u16* ATT  = wsu + 58720256;    // [32768][256]: a2
    u16* SIM  = wsu + 67108864;    // [128][256][256]
    u16* SS   = wsu + 75497472;    // [128][256][256]
    u16* WiT  = wsu + 83886080;    // [256][320]
    u16* WaT  = wsu + 83968000;    // [256][256]
    u16* WpT  = wsu + 84033536;    // [256][640]
    u16* WcT  = wsu + 84197376;    // [512][448]
    float* fb = (float*)(wsu + 84426752);
    float* POOL = fb;              // [128][800]
    float* M1f  = fb + 102400;     // [128][256]
    float* M2f  = fb + 135168;

    const long long sL = 65536;    // 256*256 per-batch stride (F/ATT/SIM/SS)
    const long long sC448 = 114688;   // 256*448
    const long long sH = 163840;      // 256*640

    zero_pool<<<400, 256, 0, stream>>>(POOL);
    make_mask<<<NB, 256, 0, stream>>>(x1, M1f);
    make_mask<<<NB, 256, 0, stream>>>(x2, M2f);
    prep_w<<<(256 * 320) / 256, 256, 0, stream>>>(Wi, 300, 200, WiT, 320, 256 * 320, 300, 320);
    prep_w<<<(256 * 256) / 256, 256, 0, stream>>>(Wa, 200, 200, WaT, 256, 256 * 256, 200, 256);
    prep_w<<<(256 * 640) / 256, 256, 0, stream>>>(Wp, 600, 200, WpT, 640, 256 * 640, 300, 320);
    prep_w<<<(512 * 448) / 256, 256, 0, stream>>>(Wc, 400, 400, WcT, 448, 512 * 448, 400, 448);

    // ---- stage A per side ------------------------------------------------
    for (int s = 0; s < 2; ++s) {
        const int* xs = s ? x2 : x1;
        u16* CMP = s ? CMP2 : CMP1;
        gather_norm<<<8192, 256, 0, stream>>>(xs, emb, H);
        // f = relu(e @ Wi + bi) -> F
        gemm<0, true, true, false, false, false><<<dim3(1, 256, 1), 512, 0, stream>>>(
            H, 640, 0, WiT, 320, 0, F, 256, 0, bi, 200,
            nullptr, nullptr, nullptr, 0, nullptr, 320, 0, 256);
        // att = f @ f^T (batched) -> SIM
        gemm<0, false, false, false, false, true><<<dim3(1, 2, NB), 512, 0, stream>>>(
            F, 256, sL, F, 256, sL, SIM, 256, sL, nullptr, 0,
            nullptr, nullptr, nullptr, 0, nullptr, 256, 0, 256);
        row_softmax<true><<<32768, 256, 0, stream>>>(SIM, b_dist);
        // xp = softmax(att) @ e -> H cols 320:640
        gemm<1, false, false, false, false, true><<<dim3(2, 2, NB), 512, 0, stream>>>(
            SIM, 256, sL, H, 640, sH, H + 320, 640, sH, nullptr, 0,
            nullptr, nullptr, nullptr, 0, nullptr, 256, 320, 320);
        // P = h @ Wp + bp -> CMP cols 0:256
        gemm<0, true, false, false, false, false><<<dim3(1, 256, 1), 512, 0, stream>>>(
            H, 640, 0, WpT, 640, 0, CMP, 448, 0, bp, 200,
            nullptr, nullptr, nullptr, 0, nullptr, 640, 0, 256);
    }

    // ---- cross attention ---------------------------------------------------
    // a1 = relu(P1 @ Wa + ba) -> F ; a2 -> ATT
    gemm<0, true, true, false, false, false><<<dim3(1, 256, 1), 512, 0, stream>>>(
        CMP1, 448, 0, WaT, 256, 0, F, 256, 0, ba, 200,
        nullptr, nullptr, nullptr, 0, nullptr, 256, 0, 256);
    gemm<0, true, true, false, false, false><<<dim3(1, 256, 1), 512, 0, stream>>>(
        CMP2, 448, 0, WaT, 256, 0, ATT, 256, 0, ba, 200,
        nullptr, nullptr, nullptr, 0, nullptr, 256, 0, 256);
    // sim = (a1 @ a2^T) * m1 x m2 -> SIM ; sim^T = (a2 @ a1^T) * m2 x m1 -> SS
    gemm<0, false, false, true, false, true><<<dim3(1, 2, NB), 512, 0, stream>>>(
        F, 256, sL, ATT, 256, sL, SIM, 256, sL, nullptr, 0,
        M1f, M2f, nullptr, 0, nullptr, 256, 0, 256);
    gemm<0, false, false, true, false, true><<<dim3(1, 2, NB), 512, 0, stream>>>(
        ATT, 256, sL, F, 256, sL, SS, 256, sL, nullptr, 0,
        M2f, M1f, nullptr, 0, nullptr, 256, 0, 256);
    row_softmax<false><<<32768, 256, 0, stream>>>(SIM, nullptr);
    row_softmax<false><<<32768, 256, 0, stream>>>(SS, nullptr);
    // beta = softmax(sim) @ P2 -> CMP1 cols 200:448 (cols>=400 become 0)
    gemm<1, false, false, false, false, true><<<dim3(1, 2, NB), 512, 0, stream>>>(
        SIM, 256, sL, CMP2, 448, sC448, CMP1 + 200, 448, sC448, nullptr, 0,
        nullptr, nullptr, nullptr, 0, nullptr, 256, 200, 248);
    // alpha = softmax(sim^T) @ P1 -> CMP2 cols 200:448
    gemm<1, false, false, false, false, true><<<dim3(1, 2, NB), 512, 0, stream>>>(
        SS, 256, sL, CMP1, 448, sC448, CMP2 + 200, 448, sC448, nullptr, 0,
        nullptr, nullptr, nullptr, 0, nullptr, 256, 200, 248);

    // ---- fused compare + masked pool ---------------------------------------
    gemm<0, true, true, false, true, false><<<dim3(2, 256, 1), 512, 0, stream>>>(
        CMP1, 448, 0, WcT, 448, 0, nullptr, 0, 0, bc, 400,
        nullptr, nullptr, POOL, 0, M1f, 448, 0, 400);
    gemm<0, true, true, false, true, false><<<dim3(2, 256, 1), 512, 0, stream>>>(
        CMP2, 448, 0, WcT, 448, 0, nullptr, 0, 0, bc, 400,
        nullptr, nullptr, POOL, 400, M2f, 448, 0, 400);

    final_fc<<<NB, 256, 0, stream>>>(POOL, Wg, bg, out);
}

// Round 7
// 291.003 us; speedup vs baseline: 1.4628x; 1.4570x over previous
//
#include <hip/hip_runtime.h>
#include <math.h>

#define LSEQ 256
#define NB   128

typedef unsigned short u16;
typedef unsigned int   u32;
typedef __attribute__((ext_vector_type(8))) short bf16x8;  // 8 bf16 = 4 VGPR
typedef __attribute__((ext_vector_type(4))) float f32x4;

static __device__ __forceinline__ u16 f2bf(float x) {
    union { float f; u32 u; } v; v.f = x;
    const u32 r = v.u + 0x7fffu + ((v.u >> 16) & 1u);   // RNE
    return (u16)(r >> 16);
}
static __device__ __forceinline__ float bf2f(u16 u) {
    union { u32 i; float f; } v; v.i = ((u32)u) << 16; return v.f;
}
// async global->LDS, 16B per lane, dest = wave-uniform base + lane*16
static __device__ __forceinline__ void glds16(const u16* src, u16* dst) {
    __builtin_amdgcn_global_load_lds(
        (const __attribute__((address_space(1))) u32*)src,
        (__attribute__((address_space(3))) u32*)dst, 16, 0, 0);
}

// ---------------------------------------------------------------------------
// bf16 MFMA GEMM. Block = 128 rows x 256 cols, 512 threads = 8 waves (2x4),
// wave tile 64x64 (4x4 fragments of 16x16x32). BK=64.
// A: bf16 row-major MxK (lda, K mult of 64). glds-staged, XOR-swizzled LDS.
// B: BMODE 0 -> bf16 [N][K], glds-staged. BMODE 1 -> bf16 [K][N],
//    reg-transpose staged, cols >= Bn read as 0.
// EPI 0: C store (+bias for gc<Nbias, relu).
// EPI 1: fused row-softmax over the full 256-wide row (block holds whole
//        rows): optional multiplicative masks m1[i]*m2[j] and distance bias
//        b_dist*(|i-j|>=10) BEFORE softmax; probs stored bf16.
// EPI 2: fused compare epilogue: pool[b][side*400+gc] += relu(acc+bc)*mask.
// DUAL: batches bz>=128 switch to A2/B2/C2/m1b/m2b with b = bz-128.
// ---------------------------------------------------------------------------
template<int BMODE, int EPI, bool BIAS, bool RELU, bool DUAL>
__global__ __launch_bounds__(512)
void gemm(const u16* __restrict__ A, const u16* __restrict__ A2, int lda, long long sA,
          const u16* __restrict__ B, const u16* __restrict__ B2, int ldb, long long sB,
          u16* __restrict__ C, u16* __restrict__ C2, int ldc, long long sC,
          const float* __restrict__ bias, int Nbias,
          const float* __restrict__ m1, const float* __restrict__ m2,
          const float* __restrict__ m1b, const float* __restrict__ m2b,
          const float* __restrict__ b_dist,
          float* __restrict__ pool, const float* __restrict__ pmask,
          int K, int Bn, int Nwrite)
{
    __shared__ u16 As[128 * 64];   // 16 KB
    __shared__ u16 Bs[256 * 64];   // 32 KB

    const int bz = blockIdx.z;
    int b = bz;
    const u16* Abase = A; const u16* Bbase = B; u16* Cbase = C;
    const float* mm1 = m1; const float* mm2 = m2;
    if (DUAL && bz >= 128) {
        b = bz - 128; Abase = A2; Bbase = B2; Cbase = C2; mm1 = m1b; mm2 = m2b;
    }
    const u16* Ab = Abase + (long long)b * sA;
    const u16* Bb = Bbase + (long long)b * sB;
    const int m0 = blockIdx.y * 128;
    const int n0 = blockIdx.x * 256;
    const int t = threadIdx.x;
    const int lane = t & 63;
    const int w = t >> 6;          // 0..7
    const int wm = w >> 2;         // 0..1
    const int wn = w & 3;          // 0..3
    const int lr = lane & 15;
    const int lg = lane >> 4;      // 0..3

    f32x4 acc[4][4] = {};

    for (int k0 = 0; k0 < K; k0 += 64) {
        // ---- stage A: 16 KB = 16 chunks of 1KB; wave w -> chunks 2w,2w+1
#pragma unroll
        for (int i = 0; i < 2; ++i) {
            const int ch = w * 2 + i;
            const int row = (ch << 3) + (lane >> 3);
            const int slot = (lane & 7) ^ (row & 7);
            glds16(Ab + (long long)(m0 + row) * lda + k0 + (slot << 3),
                   &As[ch << 9]);
        }
        // ---- stage B
        if (BMODE == 0) {
#pragma unroll
            for (int i = 0; i < 4; ++i) {
                const int ch = w * 4 + i;
                const int row = (ch << 3) + (lane >> 3);
                const int slot = (lane & 7) ^ (row & 7);
                glds16(Bb + (long long)(n0 + row) * ldb + k0 + (slot << 3),
                       &Bs[ch << 9]);
            }
        } else {
            // B is [K][N]: thread covers 8k x 4n, transpose in regs
            const int n4 = (t & 63) << 2;    // 0..252
            const int k8 = w << 3;           // 0..56
            union { uint2 q2[8]; u16 s[32]; } uq;
#pragma unroll
            for (int i = 0; i < 8; ++i)
                uq.q2[i] = *reinterpret_cast<const uint2*>(
                    Bb + (long long)(k0 + k8 + i) * ldb + n0 + n4);
#pragma unroll
            for (int j = 0; j < 4; ++j) {
                u32 v0 = 0, v1 = 0, v2 = 0, v3 = 0;
                if (n0 + n4 + j < Bn) {
                    v0 = (u32)uq.s[j]      | ((u32)uq.s[4 + j]  << 16);
                    v1 = (u32)uq.s[8 + j]  | ((u32)uq.s[12 + j] << 16);
                    v2 = (u32)uq.s[16 + j] | ((u32)uq.s[20 + j] << 16);
                    v3 = (u32)uq.s[24 + j] | ((u32)uq.s[28 + j] << 16);
                }
                const int row = n4 + j;
                const int slot = w ^ (row & 7);
                *reinterpret_cast<uint4*>(&Bs[row * 64 + (slot << 3)]) =
                    make_uint4(v0, v1, v2, v3);
            }
        }
        __syncthreads();

        // ---- fragments + MFMA (2 k-halves of 32)
#pragma unroll
        for (int kk = 0; kk < 2; ++kk) {
            bf16x8 af[4], bf[4];
#pragma unroll
            for (int mi = 0; mi < 4; ++mi) {
                const int row = wm * 64 + mi * 16 + lr;
                const int slot = ((kk << 2) + lg) ^ (row & 7);
                af[mi] = *reinterpret_cast<const bf16x8*>(&As[row * 64 + (slot << 3)]);
            }
#pragma unroll
            for (int ni = 0; ni < 4; ++ni) {
                const int row = wn * 64 + ni * 16 + lr;
                const int slot = ((kk << 2) + lg) ^ (row & 7);
                bf[ni] = *reinterpret_cast<const bf16x8*>(&Bs[row * 64 + (slot << 3)]);
            }
#pragma unroll
            for (int mi = 0; mi < 4; ++mi)
#pragma unroll
                for (int ni = 0; ni < 4; ++ni)
                    acc[mi][ni] = __builtin_amdgcn_mfma_f32_16x16x32_bf16(
                        af[mi], bf[ni], acc[mi][ni], 0, 0, 0);
        }
        __syncthreads();
    }

    const int rbase = lg << 2;
    if (EPI == 0) {
        u16* Cb = Cbase + (long long)b * sC;
#pragma unroll
        for (int ni = 0; ni < 4; ++ni) {
            const int gc = n0 + wn * 64 + ni * 16 + lr;
            if (gc >= Nwrite) continue;
            float bcv = 0.f;
            if (BIAS) bcv = (gc < Nbias) ? bias[gc] : 0.f;
#pragma unroll
            for (int mi = 0; mi < 4; ++mi) {
#pragma unroll
                for (int r = 0; r < 4; ++r) {
                    const long long gr = m0 + wm * 64 + mi * 16 + rbase + r;
                    float x = acc[mi][ni][r];
                    if (BIAS) x += bcv;
                    if (RELU) x = fmaxf(x, 0.f);
                    Cb[gr * ldc + gc] = f2bf(x);
                }
            }
        }
    } else if (EPI == 1) {
        // ---- fused row softmax over full 256-wide rows -------------------
        u16* Cb = Cbase + (long long)b * sC;
        // pre-softmax transforms
        float m1v[4][4], m2v[4];
        if (mm1 != nullptr) {
#pragma unroll
            for (int mi = 0; mi < 4; ++mi)
#pragma unroll
                for (int r = 0; r < 4; ++r)
                    m1v[mi][r] = mm1[b * 256 + m0 + wm * 64 + mi * 16 + rbase + r];
#pragma unroll
            for (int ni = 0; ni < 4; ++ni)
                m2v[ni] = mm2[b * 256 + wn * 64 + ni * 16 + lr];
        }
        float bdv = 0.f;
        if (b_dist != nullptr) bdv = b_dist[0];
#pragma unroll
        for (int mi = 0; mi < 4; ++mi)
#pragma unroll
            for (int ni = 0; ni < 4; ++ni)
#pragma unroll
                for (int r = 0; r < 4; ++r) {
                    float x = acc[mi][ni][r];
                    if (mm1 != nullptr) x *= m1v[mi][r] * m2v[ni];
                    if (b_dist != nullptr) {
                        const int irow = m0 + wm * 64 + mi * 16 + rbase + r;
                        const int jcol = wn * 64 + ni * 16 + lr;
                        const int d = irow > jcol ? irow - jcol : jcol - irow;
                        if (d >= 10) x += bdv;
                    }
                    acc[mi][ni][r] = x;
                }
        float* red  = reinterpret_cast<float*>(As);   // [128][4]
        float* red2 = red + 512;                      // [128][4]
        // row max (cross-wave via LDS)
        float mx[4][4];
#pragma unroll
        for (int mi = 0; mi < 4; ++mi)
#pragma unroll
            for (int r = 0; r < 4; ++r) {
                float m_ = fmaxf(fmaxf(acc[mi][0][r], acc[mi][1][r]),
                                 fmaxf(acc[mi][2][r], acc[mi][3][r]));
#pragma unroll
                for (int o = 1; o <= 8; o <<= 1) m_ = fmaxf(m_, __shfl_xor(m_, o, 64));
                mx[mi][r] = m_;
            }
        if (lr == 0) {
#pragma unroll
            for (int mi = 0; mi < 4; ++mi)
#pragma unroll
                for (int r = 0; r < 4; ++r)
                    red[(wm * 64 + mi * 16 + rbase + r) * 4 + wn] = mx[mi][r];
        }
        __syncthreads();
        // exp + row sum
        float sm[4][4];
#pragma unroll
        for (int mi = 0; mi < 4; ++mi)
#pragma unroll
            for (int r = 0; r < 4; ++r) {
                const int row = wm * 64 + mi * 16 + rbase + r;
                const float m_ = fmaxf(fmaxf(red[row * 4 + 0], red[row * 4 + 1]),
                                       fmaxf(red[row * 4 + 2], red[row * 4 + 3]));
                float s_ = 0.f;
#pragma unroll
                for (int ni = 0; ni < 4; ++ni) {
                    const float e_ = expf(acc[mi][ni][r] - m_);
                    acc[mi][ni][r] = e_;
                    s_ += e_;
                }
#pragma unroll
                for (int o = 1; o <= 8; o <<= 1) s_ += __shfl_xor(s_, o, 64);
                sm[mi][r] = s_;
            }
        if (lr == 0) {
#pragma unroll
            for (int mi = 0; mi < 4; ++mi)
#pragma unroll
                for (int r = 0; r < 4; ++r)
                    red2[(wm * 64 + mi * 16 + rbase + r) * 4 + wn] = sm[mi][r];
        }
        __syncthreads();
#pragma unroll
        for (int mi = 0; mi < 4; ++mi)
#pragma unroll
            for (int r = 0; r < 4; ++r) {
                const int row = wm * 64 + mi * 16 + rbase + r;
                const float s_ = red2[row * 4 + 0] + red2[row * 4 + 1]
                               + red2[row * 4 + 2] + red2[row * 4 + 3];
                const float rs = 1.0f / s_;
#pragma unroll
                for (int ni = 0; ni < 4; ++ni) {
                    const int gc = wn * 64 + ni * 16 + lr;
                    Cb[(long long)(m0 + row) * ldc + gc] = f2bf(acc[mi][ni][r] * rs);
                }
            }
    } else {
        // ---- fused compare epilogue: masked row-pool --------------------
        __syncthreads();
        float* pool_s = reinterpret_cast<float*>(As);
        for (int i = t; i < 256; i += 512) pool_s[i] = 0.f;
        __syncthreads();
        const int b_lin = m0 >> 8;          // 0..255 across both sides
        const int side  = b_lin >> 7;
        const int bb    = b_lin & 127;
        const float* mk = pmask + b_lin * 256 + (m0 & 255);
        float mrow[4][4];
#pragma unroll
        for (int mi = 0; mi < 4; ++mi)
#pragma unroll
            for (int r = 0; r < 4; ++r)
                mrow[mi][r] = mk[wm * 64 + mi * 16 + rbase + r];
#pragma unroll
        for (int ni = 0; ni < 4; ++ni) {
            const int lc = wn * 64 + ni * 16 + lr;
            const int gc = n0 + lc;
            const float bcv = (BIAS && gc < Nbias) ? bias[gc] : 0.f;
            float cs = 0.f;
#pragma unroll
            for (int mi = 0; mi < 4; ++mi)
#pragma unroll
                for (int r = 0; r < 4; ++r)
                    cs += fmaxf(acc[mi][ni][r] + bcv, 0.f) * mrow[mi][r];
            cs += __shfl_xor(cs, 16, 64);
            cs += __shfl_xor(cs, 32, 64);
            if (lg == 0) atomicAdd(&pool_s[lc], cs);
        }
        __syncthreads();
        for (int i = t; i < 256; i += 512) {
            const int gc = n0 + i;
            if (gc < Nwrite) atomicAdd(&pool[bb * 800 + side * 400 + gc], pool_s[i]);
        }
    }
}

// ---------------------------------------------------------------------------
// weight prep: dst[n][k] (bf16) = src[srcRow(k)][n] or 0.
// ---------------------------------------------------------------------------
__global__ __launch_bounds__(256)
void prep_w(const float* __restrict__ src, int srcRows, int srcCols,
            u16* __restrict__ dst, int dstCols, int dstTotal,
            int seg1, int seg2start)
{
    const int idx = blockIdx.x * 256 + threadIdx.x;
    if (idx >= dstTotal) return;
    const int n = idx / dstCols, k = idx - n * dstCols;
    int sr = -1;
    if (k < seg1) sr = k;
    else if (k >= seg2start && (k - seg2start) < (srcRows - seg1)) sr = seg1 + (k - seg2start);
    u16 v = 0;
    if (n < srcCols && sr >= 0) v = f2bf(src[(long long)sr * srcCols + n]);
    dst[idx] = v;
}

__global__ __launch_bounds__(256)
void zero_pool(float* __restrict__ p)
{
    p[blockIdx.x * 256 + threadIdx.x] = 0.f;
}

// mask[b][l] = (l < count_nonzero(x[b,:])) ? 1 : 0
__global__ __launch_bounds__(256)
void make_mask(const int* __restrict__ x, float* __restrict__ mask)
{
    const int b = blockIdx.x;
    const int t = threadIdx.x;
    int nz = (x[b * LSEQ + t] != 0) ? 1 : 0;
#pragma unroll
    for (int o = 32; o; o >>= 1) nz += __shfl_xor(nz, o, 64);
    __shared__ int red[4];
    if ((t & 63) == 0) red[t >> 6] = nz;
    __syncthreads();
    const int size = red[0] + red[1] + red[2] + red[3];
    mask[b * LSEQ + t] = (t < size) ? 1.0f : 0.0f;
}

// gather + L2-normalize -> h[row][0:320] bf16 (cols 300-319 zero), pitch 640
__global__ __launch_bounds__(256)
void gather_norm(const int* __restrict__ x, const float* __restrict__ emb,
                 u16* __restrict__ h)
{
    const int t = threadIdx.x;
    const int lane = t & 63;
    const long long row = (long long)blockIdx.x * 4 + (t >> 6);
    const int tok = x[row];
    const float* er = emb + (long long)tok * 300;
    float vals[5];
    float ss = 0.f;
#pragma unroll
    for (int i = 0; i < 5; ++i) {
        const int c = lane + i * 64;
        const float v = (c < 300) ? er[c] : 0.f;
        vals[i] = v;
        ss = fmaf(v, v, ss);
    }
#pragma unroll
    for (int o = 32; o; o >>= 1) ss += __shfl_xor(ss, o, 64);
    const float inv = 1.0f / sqrtf(ss);
    u16* out = h + row * 640;
#pragma unroll
    for (int i = 0; i < 5; ++i) {
        const int c = lane + i * 64;
        out[c] = f2bf(vals[i] * inv);
    }
}

__global__ __launch_bounds__(256)
void final_fc(const float* __restrict__ pooled, const float* __restrict__ Wg,
              const float* __restrict__ bg, float* __restrict__ out)
{
    const int b = blockIdx.x;
    const int t = threadIdx.x;
    float a0 = 0.f, a1 = 0.f, a2 = 0.f;
    for (int k = t; k < 800; k += 256) {
        const float p = pooled[(long long)b * 800 + k];
        a0 = fmaf(p, Wg[k * 3 + 0], a0);
        a1 = fmaf(p, Wg[k * 3 + 1], a1);
        a2 = fmaf(p, Wg[k * 3 + 2], a2);
    }
#pragma unroll
    for (int o = 32; o; o >>= 1) {
        a0 += __shfl_xor(a0, o, 64);
        a1 += __shfl_xor(a1, o, 64);
        a2 += __shfl_xor(a2, o, 64);
    }
    __shared__ float r0[4], r1[4], r2[4];
    if ((t & 63) == 0) { r0[t >> 6] = a0; r1[t >> 6] = a1; r2[t >> 6] = a2; }
    __syncthreads();
    if (t == 0) {
        out[b * 3 + 0] = r0[0] + r0[1] + r0[2] + r0[3] + bg[0];
        out[b * 3 + 1] = r1[0] + r1[1] + r1[2] + r1[3] + bg[1];
        out[b * 3 + 2] = r2[0] + r2[1] + r2[2] + r2[3] + bg[2];
    }
}

// ---------------------------------------------------------------------------
extern "C" void kernel_launch(void* const* d_in, const int* in_sizes, int n_in,
                              void* d_out, int out_size, void* d_ws, size_t ws_size,
                              hipStream_t stream)
{
    (void)in_sizes; (void)n_in; (void)out_size; (void)ws_size;

    const int*   x1     = (const int*)  d_in[0];
    const int*   x2     = (const int*)  d_in[1];
    const float* emb    = (const float*)d_in[2];
    const float* Wi     = (const float*)d_in[3];
    const float* bi     = (const float*)d_in[4];
    const float* b_dist = (const float*)d_in[5];
    const float* Wp     = (const float*)d_in[6];
    const float* bp     = (const float*)d_in[7];
    const float* Wa     = (const float*)d_in[8];
    const float* ba     = (const float*)d_in[9];
    const float* Wc     = (const float*)d_in[10];
    const float* bc     = (const float*)d_in[11];
    const float* Wg     = (const float*)d_in[12];
    const float* bg     = (const float*)d_in[13];
    float* out = (float*)d_out;

    // ---- workspace (bf16 u16 unless noted), ~178 MB ----------------------
    // live ranges: H: gather..P-GEMM (then sim-probs alias it)
    //              CMP: intra-probs (att..xp), then P/beta/alpha..compare
    //              FA: f (f..att), then a (a..sim)
    u16* wsu  = (u16*)d_ws;
    u16* H    = wsu;                       // [65536][640]
    u16* CMP  = wsu + 41943040;            // [65536][448] (side0 rows 0..32767)
    u16* FA   = wsu + 71303168;            // [65536][256]
    u16* PRI  = CMP;                       // intra probs [256][256][256] alias
    u16* SIMP = H;                         // sim probs  [256][256][256] alias
    u16* WiT  = wsu + 88080384;            // [256][320]
    u16* WaT  = wsu + 88162304;            // [256][256]
    u16* WpT  = wsu + 88227840;            // [256][640]
    u16* WcT  = wsu + 88391680;            // [512][448]
    float* fb = (float*)(wsu + 88621056);
    float* POOL = fb;                      // [128][800]
    float* M1f  = fb + 102400;             // [128][256]
    float* M2f  = fb + 135168;             // contiguous after M1f

    u16* H2   = H   + (long long)32768 * 640;
    u16* CMP2 = CMP + (long long)32768 * 448;
    u16* FA2  = FA  + (long long)32768 * 256;

    const long long sL = 65536;        // 256x256 batch stride
    const long long sC448 = 114688;    // 256x448
    const long long sH = 163840;       // 256x640

    zero_pool<<<400, 256, 0, stream>>>(POOL);
    make_mask<<<NB, 256, 0, stream>>>(x1, M1f);
    make_mask<<<NB, 256, 0, stream>>>(x2, M2f);
    prep_w<<<(256 * 320) / 256, 256, 0, stream>>>(Wi, 300, 200, WiT, 320, 256 * 320, 300, 320);
    prep_w<<<(256 * 256) / 256, 256, 0, stream>>>(Wa, 200, 200, WaT, 256, 256 * 256, 200, 256);
    prep_w<<<(256 * 640) / 256, 256, 0, stream>>>(Wp, 600, 200, WpT, 640, 256 * 640, 300, 320);
    prep_w<<<(512 * 448) / 256, 256, 0, stream>>>(Wc, 400, 400, WcT, 448, 512 * 448, 400, 448);

    gather_norm<<<8192, 256, 0, stream>>>(x1, emb, H);
    gather_norm<<<8192, 256, 0, stream>>>(x2, emb, H2);

    // f = relu(e @ Wi + bi), both sides (M=65536) -> FA
    gemm<0, 0, true, true, false><<<dim3(1, 512, 1), 512, 0, stream>>>(
        H, nullptr, 640, 0, WiT, nullptr, 320, 0, FA, nullptr, 256, 0,
        bi, 200, nullptr, nullptr, nullptr, nullptr, nullptr, nullptr, nullptr,
        320, 0, 256);
    // att + dbias + row-softmax fused (256 batches) -> PRI
    gemm<0, 1, false, false, false><<<dim3(1, 2, 256), 512, 0, stream>>>(
        FA, nullptr, 256, sL, FA, nullptr, 256, sL, PRI, nullptr, 256, sL,
        nullptr, 0, nullptr, nullptr, nullptr, nullptr, b_dist, nullptr, nullptr,
        256, 0, 256);
    // xp = prob @ e -> H cols 320:640 (256 batches)
    gemm<1, 0, false, false, false><<<dim3(2, 2, 256), 512, 0, stream>>>(
        PRI, nullptr, 256, sL, H, nullptr, 640, sH, H + 320, nullptr, 640, sH,
        nullptr, 0, nullptr, nullptr, nullptr, nullptr, nullptr, nullptr, nullptr,
        256, 320, 320);
    // P = h @ Wp + bp (M=65536) -> CMP cols 0:256
    gemm<0, 0, true, false, false><<<dim3(1, 512, 1), 512, 0, stream>>>(
        H, nullptr, 640, 0, WpT, nullptr, 640, 0, CMP, nullptr, 448, 0,
        bp, 200, nullptr, nullptr, nullptr, nullptr, nullptr, nullptr, nullptr,
        640, 0, 256);
    // a = relu(P @ Wa + ba) (M=65536) -> FA
    gemm<0, 0, true, true, false><<<dim3(1, 512, 1), 512, 0, stream>>>(
        CMP, nullptr, 448, 0, WaT, nullptr, 256, 0, FA, nullptr, 256, 0,
        ba, 200, nullptr, nullptr, nullptr, nullptr, nullptr, nullptr, nullptr,
        256, 0, 256);
    // sim (bz<128: a1@a2^T, masks m1*m2) / simT (bz>=128: a2@a1^T, swapped)
    // + row-softmax fused -> SIMP
    gemm<0, 1, false, false, true><<<dim3(1, 2, 256), 512, 0, stream>>>(
        FA, FA2, 256, sL, FA2, FA, 256, sL, SIMP, SIMP + 128 * sL, 256, sL,
        nullptr, 0, M1f, M2f, M2f, M1f, nullptr, nullptr, nullptr,
        256, 0, 256);
    // beta = probs@P2 -> CMP1 cols 200:448 ; alpha = probsT@P1 -> CMP2 cols 200:448
    gemm<1, 0, false, false, true><<<dim3(1, 2, 256), 512, 0, stream>>>(
        SIMP, SIMP + 128 * sL, 256, sL, CMP2, CMP, 448, sC448,
        CMP + 200, CMP2 + 200, 448, sC448,
        nullptr, 0, nullptr, nullptr, nullptr, nullptr, nullptr, nullptr, nullptr,
        256, 200, 248);
    // compare + masked pool, both sides (M=65536)
    gemm<0, 2, true, true, false><<<dim3(2, 512, 1), 512, 0, stream>>>(
        CMP, nullptr, 448, 0, WcT, nullptr, 448, 0, nullptr, nullptr, 0, 0,
        bc, 400, nullptr, nullptr, nullptr, nullptr, nullptr, POOL, M1f,
        448, 0, 400);

    final_fc<<<NB, 256, 0, stream>>>(POOL, Wg, bg, out);
}

// Round 8
// 237.562 us; speedup vs baseline: 1.7919x; 1.2250x over previous
//
#include <hip/hip_runtime.h>
#include <math.h>

#define LSEQ 256
#define NB   128

typedef unsigned short u16;
typedef unsigned int   u32;
typedef __attribute__((ext_vector_type(8))) short bf16x8;  // 8 bf16 = 4 VGPR
typedef __attribute__((ext_vector_type(4))) float f32x4;

static __device__ __forceinline__ u16 f2bf(float x) {
    union { float f; u32 u; } v; v.f = x;
    const u32 r = v.u + 0x7fffu + ((v.u >> 16) & 1u);   // RNE
    return (u16)(r >> 16);
}
// async global->LDS, 16B per lane, dest = wave-uniform base + lane*16
static __device__ __forceinline__ void glds16(const u16* src, u16* dst) {
    __builtin_amdgcn_global_load_lds(
        (const __attribute__((address_space(1))) u32*)src,
        (__attribute__((address_space(3))) u32*)dst, 16, 0, 0);
}

// ---------------------------------------------------------------------------
// Dense bf16 MFMA GEMM (non-batched). Block = 128 rows x 256 cols, 512 thr =
// 8 waves (2x4), wave tile 64x64 (4x4 frags of 16x16x32). BK=64.
// A bf16 [M][lda] (K mult 64), B bf16 [N][ldb] (pre-transposed weights).
// EPI 0: C = (acc [+bias gc<Nbias]) [relu] ; EPI 2: fused masked row-pool.
// ---------------------------------------------------------------------------
template<int EPI, bool BIAS, bool RELU>
__global__ __launch_bounds__(512)
void gemm(const u16* __restrict__ A, int lda,
          const u16* __restrict__ B, int ldb,
          u16* __restrict__ C, int ldc,
          const float* __restrict__ bias, int Nbias,
          float* __restrict__ pool, const float* __restrict__ pmask,
          int K, int Nwrite)
{
    __shared__ u16 As[128 * 64];   // 16 KB
    __shared__ u16 Bs[256 * 64];   // 32 KB

    const int m0 = blockIdx.y * 128;
    const int n0 = blockIdx.x * 256;
    const int t = threadIdx.x;
    const int lane = t & 63;
    const int w = t >> 6;
    const int wm = w >> 2;
    const int wn = w & 3;
    const int lr = lane & 15;
    const int lg = lane >> 4;

    f32x4 acc[4][4] = {};

    for (int k0 = 0; k0 < K; k0 += 64) {
#pragma unroll
        for (int i = 0; i < 2; ++i) {
            const int ch = w * 2 + i;
            const int row = (ch << 3) + (lane >> 3);
            const int slot = (lane & 7) ^ (row & 7);
            glds16(A + (long long)(m0 + row) * lda + k0 + (slot << 3), &As[ch << 9]);
        }
#pragma unroll
        for (int i = 0; i < 4; ++i) {
            const int ch = w * 4 + i;
            const int row = (ch << 3) + (lane >> 3);
            const int slot = (lane & 7) ^ (row & 7);
            glds16(B + (long long)(n0 + row) * ldb + k0 + (slot << 3), &Bs[ch << 9]);
        }
        __syncthreads();
#pragma unroll
        for (int kk = 0; kk < 2; ++kk) {
            bf16x8 af[4], bf[4];
#pragma unroll
            for (int mi = 0; mi < 4; ++mi) {
                const int row = wm * 64 + mi * 16 + lr;
                const int slot = ((kk << 2) + lg) ^ (row & 7);
                af[mi] = *reinterpret_cast<const bf16x8*>(&As[row * 64 + (slot << 3)]);
            }
#pragma unroll
            for (int ni = 0; ni < 4; ++ni) {
                const int row = wn * 64 + ni * 16 + lr;
                const int slot = ((kk << 2) + lg) ^ (row & 7);
                bf[ni] = *reinterpret_cast<const bf16x8*>(&Bs[row * 64 + (slot << 3)]);
            }
#pragma unroll
            for (int mi = 0; mi < 4; ++mi)
#pragma unroll
                for (int ni = 0; ni < 4; ++ni)
                    acc[mi][ni] = __builtin_amdgcn_mfma_f32_16x16x32_bf16(
                        af[mi], bf[ni], acc[mi][ni], 0, 0, 0);
        }
        __syncthreads();
    }

    const int rbase = lg << 2;
    if (EPI == 0) {
#pragma unroll
        for (int ni = 0; ni < 4; ++ni) {
            const int gc = n0 + wn * 64 + ni * 16 + lr;
            if (gc >= Nwrite) continue;
            float bcv = 0.f;
            if (BIAS) bcv = (gc < Nbias) ? bias[gc] : 0.f;
#pragma unroll
            for (int mi = 0; mi < 4; ++mi) {
#pragma unroll
                for (int r = 0; r < 4; ++r) {
                    const long long gr = m0 + wm * 64 + mi * 16 + rbase + r;
                    float x = acc[mi][ni][r];
                    if (BIAS) x += bcv;
                    if (RELU) x = fmaxf(x, 0.f);
                    C[gr * ldc + gc] = f2bf(x);
                }
            }
        }
    } else {
        // fused compare epilogue: pool[b][side*400+gc] += relu(acc+bc)*mask[row]
        __syncthreads();
        float* pool_s = reinterpret_cast<float*>(As);
        for (int i = t; i < 256; i += 512) pool_s[i] = 0.f;
        __syncthreads();
        const int b_lin = m0 >> 8;
        const int side  = b_lin >> 7;
        const int bb    = b_lin & 127;
        const float* mk = pmask + b_lin * 256 + (m0 & 255);
        float mrow[4][4];
#pragma unroll
        for (int mi = 0; mi < 4; ++mi)
#pragma unroll
            for (int r = 0; r < 4; ++r)
                mrow[mi][r] = mk[wm * 64 + mi * 16 + rbase + r];
#pragma unroll
        for (int ni = 0; ni < 4; ++ni) {
            const int lc = wn * 64 + ni * 16 + lr;
            const int gc = n0 + lc;
            const float bcv = (BIAS && gc < Nbias) ? bias[gc] : 0.f;
            float cs = 0.f;
#pragma unroll
            for (int mi = 0; mi < 4; ++mi)
#pragma unroll
                for (int r = 0; r < 4; ++r)
                    cs += fmaxf(acc[mi][ni][r] + bcv, 0.f) * mrow[mi][r];
            cs += __shfl_xor(cs, 16, 64);
            cs += __shfl_xor(cs, 32, 64);
            if (lg == 0) atomicAdd(&pool_s[lc], cs);
        }
        __syncthreads();
        for (int i = t; i < 256; i += 512) {
            const int gc = n0 + i;
            if (gc < Nwrite) atomicAdd(&pool[bb * 800 + side * 400 + gc], pool_s[i]);
        }
    }
}

// ---------------------------------------------------------------------------
// Fused flash attention block. MODE 0 = intra: probs = softmax_k(f@f^T + dist
// bias), out = probs @ e (NV=320). MODE 1 = cross: probs = softmax_k(masked
// a_q @ a_k^T), out = probs @ P (NV=256, write 248).
// One block = one (batch, 128-row half[, variant]). 512 thr = 8 waves.
// QK phase computes SWAPPED product D[k][q] = mfma(key, query) so each
// thread's 4 acc regs are k-contiguous -> packed b64 prob writes to LDS in
// MFMA A-operand layout. PV phase: per-64-k chunk {V reg-transpose stage,
// owning-wave prob write, barrier, MFMA}.
// ---------------------------------------------------------------------------
template<int MODE>
__global__ __launch_bounds__(512)
void fattn(const u16* __restrict__ QK, u16* __restrict__ Hb,
           u16* __restrict__ CMP, u16* __restrict__ CMP2,
           const float* __restrict__ M1, const float* __restrict__ M2,
           const float* __restrict__ b_dist)
{
    constexpr int NVT = (MODE == 0) ? 5 : 4;     // V col tiles of 64
    __shared__ char shmem[57344];                 // 56 KB
    u16* Ks = (u16*)shmem;                        // [256][64] 32 KB (QK)
    u16* Qs = (u16*)(shmem + 32768);              // [128][64] 16 KB (QK, cross)
    float* red  = (float*)(shmem + 49152);        // [128][4]
    float* red2 = (float*)(shmem + 51200);        // [128][4]
    u16* Pc = (u16*)shmem;                        // [128][64] 16 KB (PV)
    u16* Vc = (u16*)(shmem + 16384);              // [NVT*64][64] <=40 KB (PV)

    const int bz = blockIdx.x;
    int b, half, rowoff, ldv, ldc, Nwrite;
    const u16 *Kp, *Qp, *Vp;
    u16* Cp;
    const float *mrow = nullptr, *mcol = nullptr;
    if (MODE == 0) {
        b = (bz & 7) + (bz >> 4) * 8;             // sibling halves share XCD
        half = (bz >> 3) & 1;
        Kp = QK + (long long)b * 65536;
        Qp = Kp;                                  // queries read from Ks
        Vp = Hb + (long long)b * 163840; ldv = 640;
        Cp = Hb + (long long)b * 163840 + half * 128 * 640 + 320;
        ldc = 640; Nwrite = 320; rowoff = half * 128;
    } else {
        const int xcd = bz & 7, j = bz >> 3;
        const int sib = j & 3;
        b = xcd + (j >> 2) * 8;
        half = sib & 1;
        const int v = sib >> 1;
        const u16* a1 = QK + (long long)b * 65536;
        const u16* a2 = QK + 32768LL * 256 + (long long)b * 65536;
        u16* P1 = CMP  + (long long)b * 114688;
        u16* P2 = CMP2 + (long long)b * 114688;
        if (v == 0) { Qp = a1 + half * 128 * 256; Kp = a2; Vp = P2;
                      Cp = P1 + half * 128 * 448 + 200;
                      mrow = M1 + b * 256 + half * 128; mcol = M2 + b * 256; }
        else        { Qp = a2 + half * 128 * 256; Kp = a1; Vp = P1;
                      Cp = P2 + half * 128 * 448 + 200;
                      mrow = M2 + b * 256 + half * 128; mcol = M1 + b * 256; }
        ldv = 448; ldc = 448; Nwrite = 248; rowoff = 0;
    }

    const int t = threadIdx.x, lane = t & 63, w = t >> 6;
    const int lr = lane & 15, lg = lane >> 4;
    const int wk = w >> 1, wr = w & 1;            // QK wave roles
    const int wr2 = w >> 2, wc = w & 3;           // PV wave roles

    // ---- QK: D[k=256][q=128] = K @ Q^T, K-feature loop 256 -------------
    f32x4 acc[4][4] = {};                         // [ki][qi]
    for (int k0 = 0; k0 < 256; k0 += 64) {
#pragma unroll
        for (int i = 0; i < 4; ++i) {
            const int ch = w * 4 + i;
            const int row = (ch << 3) + (lane >> 3);
            const int slot = (lane & 7) ^ (row & 7);
            glds16(Kp + (long long)row * 256 + k0 + (slot << 3), &Ks[ch << 9]);
        }
        if (MODE != 0) {
#pragma unroll
            for (int i = 0; i < 2; ++i) {
                const int ch = w * 2 + i;
                const int row = (ch << 3) + (lane >> 3);
                const int slot = (lane & 7) ^ (row & 7);
                glds16(Qp + (long long)row * 256 + k0 + (slot << 3), &Qs[ch << 9]);
            }
        }
        __syncthreads();
#pragma unroll
        for (int kk = 0; kk < 2; ++kk) {
            bf16x8 kf[4], qf[4];
#pragma unroll
            for (int ki = 0; ki < 4; ++ki) {
                const int row = wk * 64 + ki * 16 + lr;
                const int slot = ((kk << 2) + lg) ^ (row & 7);
                kf[ki] = *reinterpret_cast<const bf16x8*>(&Ks[row * 64 + (slot << 3)]);
            }
#pragma unroll
            for (int qi = 0; qi < 4; ++qi) {
                if (MODE == 0) {
                    const int row = rowoff + wr * 64 + qi * 16 + lr;
                    const int slot = ((kk << 2) + lg) ^ (row & 7);
                    qf[qi] = *reinterpret_cast<const bf16x8*>(&Ks[row * 64 + (slot << 3)]);
                } else {
                    const int row = wr * 64 + qi * 16 + lr;
                    const int slot = ((kk << 2) + lg) ^ (row & 7);
                    qf[qi] = *reinterpret_cast<const bf16x8*>(&Qs[row * 64 + (slot << 3)]);
                }
            }
#pragma unroll
            for (int ki = 0; ki < 4; ++ki)
#pragma unroll
                for (int qi = 0; qi < 4; ++qi)
                    acc[ki][qi] = __builtin_amdgcn_mfma_f32_16x16x32_bf16(
                        kf[ki], qf[qi], acc[ki][qi], 0, 0, 0);
        }
        __syncthreads();
    }

    // ---- pre-softmax transform ------------------------------------------
    if (MODE == 1) {
        float mr[4], mc[4][4];
#pragma unroll
        for (int qi = 0; qi < 4; ++qi) mr[qi] = mrow[wr * 64 + qi * 16 + lr];
#pragma unroll
        for (int ki = 0; ki < 4; ++ki)
#pragma unroll
            for (int r = 0; r < 4; ++r)
                mc[ki][r] = mcol[wk * 64 + ki * 16 + (lg << 2) + r];
#pragma unroll
        for (int ki = 0; ki < 4; ++ki)
#pragma unroll
            for (int qi = 0; qi < 4; ++qi)
#pragma unroll
                for (int r = 0; r < 4; ++r)
                    acc[ki][qi][r] *= mr[qi] * mc[ki][r];
    } else {
        const float bd = b_dist[0];
#pragma unroll
        for (int ki = 0; ki < 4; ++ki)
#pragma unroll
            for (int qi = 0; qi < 4; ++qi)
#pragma unroll
                for (int r = 0; r < 4; ++r) {
                    const int irow = rowoff + wr * 64 + qi * 16 + lr;
                    const int jcol = wk * 64 + ki * 16 + (lg << 2) + r;
                    const int d = irow > jcol ? irow - jcol : jcol - irow;
                    if (d >= 10) acc[ki][qi][r] += bd;
                }
    }

    // ---- softmax over k (cross-wave via LDS) -----------------------------
    float mx[4];
#pragma unroll
    for (int qi = 0; qi < 4; ++qi) {
        float m_ = -1e30f;
#pragma unroll
        for (int ki = 0; ki < 4; ++ki)
#pragma unroll
            for (int r = 0; r < 4; ++r) m_ = fmaxf(m_, acc[ki][qi][r]);
        m_ = fmaxf(m_, __shfl_xor(m_, 16, 64));
        m_ = fmaxf(m_, __shfl_xor(m_, 32, 64));
        mx[qi] = m_;
    }
    if (lg == 0) {
#pragma unroll
        for (int qi = 0; qi < 4; ++qi)
            red[(wr * 64 + qi * 16 + lr) * 4 + wk] = mx[qi];
    }
    __syncthreads();
    float sm[4];
#pragma unroll
    for (int qi = 0; qi < 4; ++qi) {
        const int row = wr * 64 + qi * 16 + lr;
        const float m_ = fmaxf(fmaxf(red[row * 4 + 0], red[row * 4 + 1]),
                               fmaxf(red[row * 4 + 2], red[row * 4 + 3]));
        float s_ = 0.f;
#pragma unroll
        for (int ki = 0; ki < 4; ++ki)
#pragma unroll
            for (int r = 0; r < 4; ++r) {
                const float e_ = expf(acc[ki][qi][r] - m_);
                acc[ki][qi][r] = e_;
                s_ += e_;
            }
        s_ += __shfl_xor(s_, 16, 64);
        s_ += __shfl_xor(s_, 32, 64);
        sm[qi] = s_;
    }
    if (lg == 0) {
#pragma unroll
        for (int qi = 0; qi < 4; ++qi)
            red2[(wr * 64 + qi * 16 + lr) * 4 + wk] = sm[qi];
    }
    __syncthreads();
#pragma unroll
    for (int qi = 0; qi < 4; ++qi) {
        const int row = wr * 64 + qi * 16 + lr;
        const float rs = 1.0f / (red2[row * 4 + 0] + red2[row * 4 + 1]
                               + red2[row * 4 + 2] + red2[row * 4 + 3]);
#pragma unroll
        for (int ki = 0; ki < 4; ++ki)
#pragma unroll
            for (int r = 0; r < 4; ++r) acc[ki][qi][r] *= rs;
    }
    __syncthreads();   // red/red2 region about to be overwritten by Vc

    // ---- PV: out[q=128][NV] = probs @ V, k loop in 4 chunks of 64 --------
    f32x4 opv[4][NVT] = {};
    for (int c = 0; c < 4; ++c) {
        // stage V chunk [n][k] via reg-transpose
        {
            const int n4 = (t & 63) << 2;
            const int k8 = (t >> 6) << 3;
            union { uint2 q2[8]; u16 s[32]; } uq;
#pragma unroll
            for (int i = 0; i < 8; ++i)
                uq.q2[i] = *reinterpret_cast<const uint2*>(
                    Vp + (long long)(c * 64 + k8 + i) * ldv + n4);
#pragma unroll
            for (int j = 0; j < 4; ++j) {
                const int row = n4 + j;
                const u32 v0 = (u32)uq.s[j]      | ((u32)uq.s[4 + j]  << 16);
                const u32 v1 = (u32)uq.s[8 + j]  | ((u32)uq.s[12 + j] << 16);
                const u32 v2 = (u32)uq.s[16 + j] | ((u32)uq.s[20 + j] << 16);
                const u32 v3 = (u32)uq.s[24 + j] | ((u32)uq.s[28 + j] << 16);
                const int slot = (t >> 6) ^ (row & 7);
                *reinterpret_cast<uint4*>(&Vc[row * 64 + (slot << 3)]) =
                    make_uint4(v0, v1, v2, v3);
            }
            if (NVT == 5 && t < 128) {
                const int n4b = 256 + ((t & 15) << 2);
                const int k8b = (t >> 4) << 3;
                union { uint2 q2[8]; u16 s[32]; } ub;
#pragma unroll
                for (int i = 0; i < 8; ++i)
                    ub.q2[i] = *reinterpret_cast<const uint2*>(
                        Vp + (long long)(c * 64 + k8b + i) * ldv + n4b);
#pragma unroll
                for (int j = 0; j < 4; ++j) {
                    const int row = n4b + j;
                    const u32 v0 = (u32)ub.s[j]      | ((u32)ub.s[4 + j]  << 16);
                    const u32 v1 = (u32)ub.s[8 + j]  | ((u32)ub.s[12 + j] << 16);
                    const u32 v2 = (u32)ub.s[16 + j] | ((u32)ub.s[20 + j] << 16);
                    const u32 v3 = (u32)ub.s[24 + j] | ((u32)ub.s[28 + j] << 16);
                    const int slot = (t >> 4) ^ (row & 7);
                    *reinterpret_cast<uint4*>(&Vc[row * 64 + (slot << 3)]) =
                        make_uint4(v0, v1, v2, v3);
                }
            }
        }
        // owning waves write this chunk's probs (k-contiguous b64 packs)
        if (wk == c) {
#pragma unroll
            for (int qi = 0; qi < 4; ++qi) {
                const int qrow = wr * 64 + qi * 16 + lr;
#pragma unroll
                for (int ki = 0; ki < 4; ++ki) {
                    const u32 lo = (u32)f2bf(acc[ki][qi][0]) | ((u32)f2bf(acc[ki][qi][1]) << 16);
                    const u32 hi = (u32)f2bf(acc[ki][qi][2]) | ((u32)f2bf(acc[ki][qi][3]) << 16);
                    const int slot = ((ki << 1) + (lg >> 1)) ^ (qrow & 7);
                    *reinterpret_cast<uint2*>(
                        (char*)Pc + qrow * 128 + (slot << 4) + ((lg & 1) << 3)) =
                        make_uint2(lo, hi);
                }
            }
        }
        __syncthreads();
#pragma unroll
        for (int kk = 0; kk < 2; ++kk) {
            bf16x8 pa[4], vb[NVT];
#pragma unroll
            for (int qi = 0; qi < 4; ++qi) {
                const int row = wr2 * 64 + qi * 16 + lr;
                const int slot = ((kk << 2) + lg) ^ (row & 7);
                pa[qi] = *reinterpret_cast<const bf16x8*>(&Pc[row * 64 + (slot << 3)]);
            }
#pragma unroll
            for (int vi = 0; vi < NVT; ++vi) {
                const int row = wc * (NVT * 16) + vi * 16 + lr;
                const int slot = ((kk << 2) + lg) ^ (row & 7);
                vb[vi] = *reinterpret_cast<const bf16x8*>(&Vc[row * 64 + (slot << 3)]);
            }
#pragma unroll
            for (int qi = 0; qi < 4; ++qi)
#pragma unroll
                for (int vi = 0; vi < NVT; ++vi)
                    opv[qi][vi] = __builtin_amdgcn_mfma_f32_16x16x32_bf16(
                        pa[qi], vb[vi], opv[qi][vi], 0, 0, 0);
        }
        __syncthreads();
    }

    // ---- write out --------------------------------------------------------
#pragma unroll
    for (int qi = 0; qi < 4; ++qi)
#pragma unroll
        for (int vi = 0; vi < NVT; ++vi) {
            const int gc = wc * (NVT * 16) + vi * 16 + lr;
            if (gc >= Nwrite) continue;
#pragma unroll
            for (int r = 0; r < 4; ++r) {
                const int qrow = wr2 * 64 + qi * 16 + (lg << 2) + r;
                Cp[(long long)qrow * ldc + gc] = f2bf(opv[qi][vi][r]);
            }
        }
}

// ---------------------------------------------------------------------------
// weight prep: dst[n][k] (bf16) = src[srcRow(k)][n] or 0.
// ---------------------------------------------------------------------------
__global__ __launch_bounds__(256)
void prep_w(const float* __restrict__ src, int srcRows, int srcCols,
            u16* __restrict__ dst, int dstCols, int dstTotal,
            int seg1, int seg2start)
{
    const int idx = blockIdx.x * 256 + threadIdx.x;
    if (idx >= dstTotal) return;
    const int n = idx / dstCols, k = idx - n * dstCols;
    int sr = -1;
    if (k < seg1) sr = k;
    else if (k >= seg2start && (k - seg2start) < (srcRows - seg1)) sr = seg1 + (k - seg2start);
    u16 v = 0;
    if (n < srcCols && sr >= 0) v = f2bf(src[(long long)sr * srcCols + n]);
    dst[idx] = v;
}

__global__ __launch_bounds__(256)
void zero_pool(float* __restrict__ p)
{
    p[blockIdx.x * 256 + threadIdx.x] = 0.f;
}

// mask[b][l] = (l < count_nonzero(x[b,:])) ? 1 : 0
__global__ __launch_bounds__(256)
void make_mask(const int* __restrict__ x, float* __restrict__ mask)
{
    const int b = blockIdx.x;
    const int t = threadIdx.x;
    int nz = (x[b * LSEQ + t] != 0) ? 1 : 0;
#pragma unroll
    for (int o = 32; o; o >>= 1) nz += __shfl_xor(nz, o, 64);
    __shared__ int red[4];
    if ((t & 63) == 0) red[t >> 6] = nz;
    __syncthreads();
    const int size = red[0] + red[1] + red[2] + red[3];
    mask[b * LSEQ + t] = (t < size) ? 1.0f : 0.0f;
}

// gather + L2-normalize -> h[row][0:320] bf16 (cols 300-319 zero), pitch 640
__global__ __launch_bounds__(256)
void gather_norm(const int* __restrict__ x, const float* __restrict__ emb,
                 u16* __restrict__ h)
{
    const int t = threadIdx.x;
    const int lane = t & 63;
    const long long row = (long long)blockIdx.x * 4 + (t >> 6);
    const int tok = x[row];
    const float* er = emb + (long long)tok * 300;
    float vals[5];
    float ss = 0.f;
#pragma unroll
    for (int i = 0; i < 5; ++i) {
        const int c = lane + i * 64;
        const float v = (c < 300) ? er[c] : 0.f;
        vals[i] = v;
        ss = fmaf(v, v, ss);
    }
#pragma unroll
    for (int o = 32; o; o >>= 1) ss += __shfl_xor(ss, o, 64);
    const float inv = 1.0f / sqrtf(ss);
    u16* out = h + row * 640;
#pragma unroll
    for (int i = 0; i < 5; ++i) {
        const int c = lane + i * 64;
        out[c] = f2bf(vals[i] * inv);
    }
}

__global__ __launch_bounds__(256)
void final_fc(const float* __restrict__ pooled, const float* __restrict__ Wg,
              const float* __restrict__ bg, float* __restrict__ out)
{
    const int b = blockIdx.x;
    const int t = threadIdx.x;
    float a0 = 0.f, a1 = 0.f, a2 = 0.f;
    for (int k = t; k < 800; k += 256) {
        const float p = pooled[(long long)b * 800 + k];
        a0 = fmaf(p, Wg[k * 3 + 0], a0);
        a1 = fmaf(p, Wg[k * 3 + 1], a1);
        a2 = fmaf(p, Wg[k * 3 + 2], a2);
    }
#pragma unroll
    for (int o = 32; o; o >>= 1) {
        a0 += __shfl_xor(a0, o, 64);
        a1 += __shfl_xor(a1, o, 64);
        a2 += __shfl_xor(a2, o, 64);
    }
    __shared__ float r0[4], r1[4], r2[4];
    if ((t & 63) == 0) { r0[t >> 6] = a0; r1[t >> 6] = a1; r2[t >> 6] = a2; }
    __syncthreads();
    if (t == 0) {
        out[b * 3 + 0] = r0[0] + r0[1] + r0[2] + r0[3] + bg[0];
        out[b * 3 + 1] = r1[0] + r1[1] + r1[2] + r1[3] + bg[1];
        out[b * 3 + 2] = r2[0] + r2[1] + r2[2] + r2[3] + bg[2];
    }
}

// ---------------------------------------------------------------------------
extern "C" void kernel_launch(void* const* d_in, const int* in_sizes, int n_in,
                              void* d_out, int out_size, void* d_ws, size_t ws_size,
                              hipStream_t stream)
{
    (void)in_sizes; (void)n_in; (void)out_size; (void)ws_size;

    const int*   x1     = (const int*)  d_in[0];
    const int*   x2     = (const int*)  d_in[1];
    const float* emb    = (const float*)d_in[2];
    const float* Wi     = (const float*)d_in[3];
    const float* bi     = (const float*)d_in[4];
    const float* b_dist = (const float*)d_in[5];
    const float* Wp     = (const float*)d_in[6];
    const float* bp     = (const float*)d_in[7];
    const float* Wa     = (const float*)d_in[8];
    const float* ba     = (const float*)d_in[9];
    const float* Wc     = (const float*)d_in[10];
    const float* bc     = (const float*)d_in[11];
    const float* Wg     = (const float*)d_in[12];
    const float* bg     = (const float*)d_in[13];
    float* out = (float*)d_out;

    // ---- workspace (bf16 u16 unless noted) -------------------------------
    u16* wsu  = (u16*)d_ws;
    u16* H    = wsu;                       // [65536][640] e|0|xp|0
    u16* CMP  = wsu + 41943040;            // [65536][448] P|beta/alpha|0
    u16* FA   = wsu + 71303168;            // [65536][256] f / a
    u16* WiT  = wsu + 88080384;            // [256][320]
    u16* WaT  = wsu + 88162304;            // [256][256]
    u16* WpT  = wsu + 88227840;            // [256][640]
    u16* WcT  = wsu + 88391680;            // [512][448]
    float* fb = (float*)(wsu + 88621056);
    float* POOL = fb;                      // [128][800]
    float* M1f  = fb + 102400;             // [128][256]
    float* M2f  = fb + 135168;             // contiguous after M1f

    u16* H2   = H   + (long long)32768 * 640;
    u16* CMP2 = CMP + (long long)32768 * 448;

    zero_pool<<<400, 256, 0, stream>>>(POOL);
    make_mask<<<NB, 256, 0, stream>>>(x1, M1f);
    make_mask<<<NB, 256, 0, stream>>>(x2, M2f);
    prep_w<<<(256 * 320) / 256, 256, 0, stream>>>(Wi, 300, 200, WiT, 320, 256 * 320, 300, 320);
    prep_w<<<(256 * 256) / 256, 256, 0, stream>>>(Wa, 200, 200, WaT, 256, 256 * 256, 200, 256);
    prep_w<<<(256 * 640) / 256, 256, 0, stream>>>(Wp, 600, 200, WpT, 640, 256 * 640, 300, 320);
    prep_w<<<(512 * 448) / 256, 256, 0, stream>>>(Wc, 400, 400, WcT, 448, 512 * 448, 400, 448);

    gather_norm<<<8192, 256, 0, stream>>>(x1, emb, H);
    gather_norm<<<8192, 256, 0, stream>>>(x2, emb, H2);

    // f = relu(e @ Wi + bi), both sides -> FA
    gemm<0, true, true><<<dim3(1, 512, 1), 512, 0, stream>>>(
        H, 640, WiT, 320, FA, 256, bi, 200, nullptr, nullptr, 320, 256);
    // fused intra attention: xp = softmax(f@f^T + dbias) @ e -> H cols 320:640
    fattn<0><<<512, 512, 0, stream>>>(FA, H, nullptr, nullptr, nullptr, nullptr, b_dist);
    // P = h @ Wp + bp -> CMP cols 0:256
    gemm<0, true, false><<<dim3(1, 512, 1), 512, 0, stream>>>(
        H, 640, WpT, 640, CMP, 448, bp, 200, nullptr, nullptr, 640, 256);
    // a = relu(P @ Wa + ba) -> FA
    gemm<0, true, true><<<dim3(1, 512, 1), 512, 0, stream>>>(
        CMP, 448, WaT, 256, FA, 256, ba, 200, nullptr, nullptr, 256, 256);
    // fused cross attention: beta/alpha -> CMP/CMP2 cols 200:448
    fattn<1><<<512, 512, 0, stream>>>(FA, nullptr, CMP, CMP2, M1f, M2f, nullptr);
    // compare + masked pool, both sides
    gemm<2, true, true><<<dim3(2, 512, 1), 512, 0, stream>>>(
        CMP, 448, WcT, 448, nullptr, 0, bc, 400, POOL, M1f, 448, 400);

    final_fc<<<NB, 256, 0, stream>>>(POOL, Wg, bg, out);
}

// Round 9
// 207.851 us; speedup vs baseline: 2.0481x; 1.1429x over previous
//
#include <hip/hip_runtime.h>
#include <math.h>

#define LSEQ 256
#define NB   128

typedef unsigned short u16;
typedef unsigned int   u32;
typedef __attribute__((ext_vector_type(8))) short bf16x8;  // 8 bf16 = 4 VGPR
typedef __attribute__((ext_vector_type(4))) float f32x4;

static __device__ __forceinline__ u16 f2bf(float x) {
    union { float f; u32 u; } v; v.f = x;
    const u32 r = v.u + 0x7fffu + ((v.u >> 16) & 1u);   // RNE
    return (u16)(r >> 16);
}
// async global->LDS, 16B per lane, dest = wave-uniform base + lane*16
static __device__ __forceinline__ void glds16(const u16* src, u16* dst) {
    __builtin_amdgcn_global_load_lds(
        (const __attribute__((address_space(1))) u32*)src,
        (__attribute__((address_space(3))) u32*)dst, 16, 0, 0);
}

// ---------------------------------------------------------------------------
// Dense bf16 MFMA GEMM (non-batched). Block = 128 rows x 256 cols, 512 thr =
// 8 waves (2x4), wave tile 64x64 (4x4 frags of 16x16x32). BK=64.
// A bf16 [M][lda] (K mult 64), B bf16 [N][ldb] (pre-transposed weights).
// EPI 0: C = (acc [+bias gc<Nbias]) [relu] ; EPI 2: fused masked row-pool.
// ---------------------------------------------------------------------------
template<int EPI, bool BIAS, bool RELU>
__global__ __launch_bounds__(512)
void gemm(const u16* __restrict__ A, int lda,
          const u16* __restrict__ B, int ldb,
          u16* __restrict__ C, int ldc,
          const float* __restrict__ bias, int Nbias,
          float* __restrict__ pool, const float* __restrict__ pmask,
          int K, int Nwrite)
{
    __shared__ u16 As[128 * 64];   // 16 KB
    __shared__ u16 Bs[256 * 64];   // 32 KB

    const int m0 = blockIdx.y * 128;
    const int n0 = blockIdx.x * 256;
    const int t = threadIdx.x;
    const int lane = t & 63;
    const int w = t >> 6;
    const int wm = w >> 2;
    const int wn = w & 3;
    const int lr = lane & 15;
    const int lg = lane >> 4;

    f32x4 acc[4][4] = {};

    for (int k0 = 0; k0 < K; k0 += 64) {
#pragma unroll
        for (int i = 0; i < 2; ++i) {
            const int ch = w * 2 + i;
            const int row = (ch << 3) + (lane >> 3);
            const int slot = (lane & 7) ^ (row & 7);
            glds16(A + (long long)(m0 + row) * lda + k0 + (slot << 3), &As[ch << 9]);
        }
#pragma unroll
        for (int i = 0; i < 4; ++i) {
            const int ch = w * 4 + i;
            const int row = (ch << 3) + (lane >> 3);
            const int slot = (lane & 7) ^ (row & 7);
            glds16(B + (long long)(n0 + row) * ldb + k0 + (slot << 3), &Bs[ch << 9]);
        }
        __syncthreads();
#pragma unroll
        for (int kk = 0; kk < 2; ++kk) {
            bf16x8 af[4], bf[4];
#pragma unroll
            for (int mi = 0; mi < 4; ++mi) {
                const int row = wm * 64 + mi * 16 + lr;
                const int slot = ((kk << 2) + lg) ^ (row & 7);
                af[mi] = *reinterpret_cast<const bf16x8*>(&As[row * 64 + (slot << 3)]);
            }
#pragma unroll
            for (int ni = 0; ni < 4; ++ni) {
                const int row = wn * 64 + ni * 16 + lr;
                const int slot = ((kk << 2) + lg) ^ (row & 7);
                bf[ni] = *reinterpret_cast<const bf16x8*>(&Bs[row * 64 + (slot << 3)]);
            }
#pragma unroll
            for (int mi = 0; mi < 4; ++mi)
#pragma unroll
                for (int ni = 0; ni < 4; ++ni)
                    acc[mi][ni] = __builtin_amdgcn_mfma_f32_16x16x32_bf16(
                        af[mi], bf[ni], acc[mi][ni], 0, 0, 0);
        }
        __syncthreads();
    }

    const int rbase = lg << 2;
    if (EPI == 0) {
#pragma unroll
        for (int ni = 0; ni < 4; ++ni) {
            const int gc = n0 + wn * 64 + ni * 16 + lr;
            if (gc >= Nwrite) continue;
            float bcv = 0.f;
            if (BIAS) bcv = (gc < Nbias) ? bias[gc] : 0.f;
#pragma unroll
            for (int mi = 0; mi < 4; ++mi) {
#pragma unroll
                for (int r = 0; r < 4; ++r) {
                    const long long gr = m0 + wm * 64 + mi * 16 + rbase + r;
                    float x = acc[mi][ni][r];
                    if (BIAS) x += bcv;
                    if (RELU) x = fmaxf(x, 0.f);
                    C[gr * ldc + gc] = f2bf(x);
                }
            }
        }
    } else {
        // fused compare epilogue: pool[b][side*400+gc] += relu(acc+bc)*mask[row]
        __syncthreads();
        float* pool_s = reinterpret_cast<float*>(As);
        for (int i = t; i < 256; i += 512) pool_s[i] = 0.f;
        __syncthreads();
        const int b_lin = m0 >> 8;
        const int side  = b_lin >> 7;
        const int bb    = b_lin & 127;
        const float* mk = pmask + b_lin * 256 + (m0 & 255);
        float mrow[4][4];
#pragma unroll
        for (int mi = 0; mi < 4; ++mi)
#pragma unroll
            for (int r = 0; r < 4; ++r)
                mrow[mi][r] = mk[wm * 64 + mi * 16 + rbase + r];
#pragma unroll
        for (int ni = 0; ni < 4; ++ni) {
            const int lc = wn * 64 + ni * 16 + lr;
            const int gc = n0 + lc;
            const float bcv = (BIAS && gc < Nbias) ? bias[gc] : 0.f;
            float cs = 0.f;
#pragma unroll
            for (int mi = 0; mi < 4; ++mi)
#pragma unroll
                for (int r = 0; r < 4; ++r)
                    cs += fmaxf(acc[mi][ni][r] + bcv, 0.f) * mrow[mi][r];
            cs += __shfl_xor(cs, 16, 64);
            cs += __shfl_xor(cs, 32, 64);
            if (lg == 0) atomicAdd(&pool_s[lc], cs);
        }
        __syncthreads();
        for (int i = t; i < 256; i += 512) {
            const int gc = n0 + i;
            if (gc < Nwrite) atomicAdd(&pool[bb * 800 + side * 400 + gc], pool_s[i]);
        }
    }
}

// ---------------------------------------------------------------------------
// Fused flash attention block. MODE 0 = intra: probs = softmax_k(f@f^T + dist
// bias), out = probs @ e (NV=320). MODE 1 = cross: probs = softmax_k(masked
// a_q @ a_k^T), out = probs @ P (NV=256, write 248).
// One block = one (batch, 128-row half[, variant]). 512 thr = 8 waves.
// QK phase computes SWAPPED product D[k][q] = mfma(key, query) so each
// thread's 4 acc regs are k-contiguous -> packed b64 prob writes to LDS in
// MFMA A-operand layout. PV phase uses T14 async-split V staging: global
// loads for chunk c+1 issue BEFORE chunk c's MFMA (latency hidden); only
// pack+ds_write sits between barriers. Chunk 0 loads issue before softmax.
// ---------------------------------------------------------------------------
template<int MODE>
__global__ __launch_bounds__(512)
void fattn(const u16* __restrict__ QK, u16* __restrict__ Hb,
           u16* __restrict__ CMP, u16* __restrict__ CMP2,
           const float* __restrict__ M1, const float* __restrict__ M2,
           const float* __restrict__ b_dist)
{
    constexpr int NVT = (MODE == 0) ? 5 : 4;     // V col tiles of 64
    __shared__ char shmem[57344];                 // 56 KB
    u16* Ks = (u16*)shmem;                        // [256][64] 32 KB (QK)
    u16* Qs = (u16*)(shmem + 32768);              // [128][64] 16 KB (QK, cross)
    float* red  = (float*)(shmem + 49152);        // [128][4]
    float* red2 = (float*)(shmem + 51200);        // [128][4]
    u16* Pc = (u16*)shmem;                        // [128][64] 16 KB (PV)
    u16* Vc = (u16*)(shmem + 16384);              // [NVT*64][64] <=40 KB (PV)

    const int bz = blockIdx.x;
    int b, half, rowoff, ldv, ldc, Nwrite;
    const u16 *Kp, *Qp, *Vp;
    u16* Cp;
    const float *mrow = nullptr, *mcol = nullptr;
    if (MODE == 0) {
        b = (bz & 7) + (bz >> 4) * 8;             // sibling halves share XCD
        half = (bz >> 3) & 1;
        Kp = QK + (long long)b * 65536;
        Qp = Kp;                                  // queries read from Ks
        Vp = Hb + (long long)b * 163840; ldv = 640;
        Cp = Hb + (long long)b * 163840 + half * 128 * 640 + 320;
        ldc = 640; Nwrite = 320; rowoff = half * 128;
    } else {
        const int xcd = bz & 7, j = bz >> 3;
        const int sib = j & 3;
        b = xcd + (j >> 2) * 8;
        half = sib & 1;
        const int v = sib >> 1;
        const u16* a1 = QK + (long long)b * 65536;
        const u16* a2 = QK + 32768LL * 256 + (long long)b * 65536;
        u16* P1 = CMP  + (long long)b * 114688;
        u16* P2 = CMP2 + (long long)b * 114688;
        if (v == 0) { Qp = a1 + half * 128 * 256; Kp = a2; Vp = P2;
                      Cp = P1 + half * 128 * 448 + 200;
                      mrow = M1 + b * 256 + half * 128; mcol = M2 + b * 256; }
        else        { Qp = a2 + half * 128 * 256; Kp = a1; Vp = P1;
                      Cp = P2 + half * 128 * 448 + 200;
                      mrow = M2 + b * 256 + half * 128; mcol = M1 + b * 256; }
        ldv = 448; ldc = 448; Nwrite = 248; rowoff = 0;
    }

    const int t = threadIdx.x, lane = t & 63, w = t >> 6;
    const int lr = lane & 15, lg = lane >> 4;
    const int wk = w >> 1, wr = w & 1;            // QK wave roles
    const int wr2 = w >> 2, wc = w & 3;           // PV wave roles

    // ---- QK: D[k=256][q=128] = K @ Q^T, K-feature loop 256 -------------
    f32x4 acc[4][4] = {};                         // [ki][qi]
    for (int k0 = 0; k0 < 256; k0 += 64) {
#pragma unroll
        for (int i = 0; i < 4; ++i) {
            const int ch = w * 4 + i;
            const int row = (ch << 3) + (lane >> 3);
            const int slot = (lane & 7) ^ (row & 7);
            glds16(Kp + (long long)row * 256 + k0 + (slot << 3), &Ks[ch << 9]);
        }
        if (MODE != 0) {
#pragma unroll
            for (int i = 0; i < 2; ++i) {
                const int ch = w * 2 + i;
                const int row = (ch << 3) + (lane >> 3);
                const int slot = (lane & 7) ^ (row & 7);
                glds16(Qp + (long long)row * 256 + k0 + (slot << 3), &Qs[ch << 9]);
            }
        }
        __syncthreads();
#pragma unroll
        for (int kk = 0; kk < 2; ++kk) {
            bf16x8 kf[4], qf[4];
#pragma unroll
            for (int ki = 0; ki < 4; ++ki) {
                const int row = wk * 64 + ki * 16 + lr;
                const int slot = ((kk << 2) + lg) ^ (row & 7);
                kf[ki] = *reinterpret_cast<const bf16x8*>(&Ks[row * 64 + (slot << 3)]);
            }
#pragma unroll
            for (int qi = 0; qi < 4; ++qi) {
                if (MODE == 0) {
                    const int row = rowoff + wr * 64 + qi * 16 + lr;
                    const int slot = ((kk << 2) + lg) ^ (row & 7);
                    qf[qi] = *reinterpret_cast<const bf16x8*>(&Ks[row * 64 + (slot << 3)]);
                } else {
                    const int row = wr * 64 + qi * 16 + lr;
                    const int slot = ((kk << 2) + lg) ^ (row & 7);
                    qf[qi] = *reinterpret_cast<const bf16x8*>(&Qs[row * 64 + (slot << 3)]);
                }
            }
#pragma unroll
            for (int ki = 0; ki < 4; ++ki)
#pragma unroll
                for (int qi = 0; qi < 4; ++qi)
                    acc[ki][qi] = __builtin_amdgcn_mfma_f32_16x16x32_bf16(
                        kf[ki], qf[qi], acc[ki][qi], 0, 0, 0);
        }
        __syncthreads();
    }

    // ---- pre-softmax transform ------------------------------------------
    if (MODE == 1) {
        float mr[4], mc[4][4];
#pragma unroll
        for (int qi = 0; qi < 4; ++qi) mr[qi] = mrow[wr * 64 + qi * 16 + lr];
#pragma unroll
        for (int ki = 0; ki < 4; ++ki)
#pragma unroll
            for (int r = 0; r < 4; ++r)
                mc[ki][r] = mcol[wk * 64 + ki * 16 + (lg << 2) + r];
#pragma unroll
        for (int ki = 0; ki < 4; ++ki)
#pragma unroll
            for (int qi = 0; qi < 4; ++qi)
#pragma unroll
                for (int r = 0; r < 4; ++r)
                    acc[ki][qi][r] *= mr[qi] * mc[ki][r];
    } else {
        const float bd = b_dist[0];
#pragma unroll
        for (int ki = 0; ki < 4; ++ki)
#pragma unroll
            for (int qi = 0; qi < 4; ++qi)
#pragma unroll
                for (int r = 0; r < 4; ++r) {
                    const int irow = rowoff + wr * 64 + qi * 16 + lr;
                    const int jcol = wk * 64 + ki * 16 + (lg << 2) + r;
                    const int d = irow > jcol ? irow - jcol : jcol - irow;
                    if (d >= 10) acc[ki][qi][r] += bd;
                }
    }

    // ---- T14: issue chunk-0 V loads now (latency hidden under softmax) ---
    const int n4  = (t & 63) << 2;
    const int k8v = (t >> 6) << 3;
    const int n4b = 256 + ((t & 15) << 2);
    const int k8b = (t >> 4) << 3;
    uint2 vreg[8], vtail[8];
#pragma unroll
    for (int i = 0; i < 8; ++i)
        vreg[i] = *reinterpret_cast<const uint2*>(Vp + (long long)(k8v + i) * ldv + n4);
    if (NVT == 5) {
        if (t < 128) {
#pragma unroll
            for (int i = 0; i < 8; ++i)
                vtail[i] = *reinterpret_cast<const uint2*>(Vp + (long long)(k8b + i) * ldv + n4b);
        }
    }

    // ---- softmax over k (cross-wave via LDS) -----------------------------
    float mx[4];
#pragma unroll
    for (int qi = 0; qi < 4; ++qi) {
        float m_ = -1e30f;
#pragma unroll
        for (int ki = 0; ki < 4; ++ki)
#pragma unroll
            for (int r = 0; r < 4; ++r) m_ = fmaxf(m_, acc[ki][qi][r]);
        m_ = fmaxf(m_, __shfl_xor(m_, 16, 64));
        m_ = fmaxf(m_, __shfl_xor(m_, 32, 64));
        mx[qi] = m_;
    }
    if (lg == 0) {
#pragma unroll
        for (int qi = 0; qi < 4; ++qi)
            red[(wr * 64 + qi * 16 + lr) * 4 + wk] = mx[qi];
    }
    __syncthreads();
    float sm[4];
#pragma unroll
    for (int qi = 0; qi < 4; ++qi) {
        const int row = wr * 64 + qi * 16 + lr;
        const float m_ = fmaxf(fmaxf(red[row * 4 + 0], red[row * 4 + 1]),
                               fmaxf(red[row * 4 + 2], red[row * 4 + 3]));
        float s_ = 0.f;
#pragma unroll
        for (int ki = 0; ki < 4; ++ki)
#pragma unroll
            for (int r = 0; r < 4; ++r) {
                const float e_ = __expf(acc[ki][qi][r] - m_);
                acc[ki][qi][r] = e_;
                s_ += e_;
            }
        s_ += __shfl_xor(s_, 16, 64);
        s_ += __shfl_xor(s_, 32, 64);
        sm[qi] = s_;
    }
    if (lg == 0) {
#pragma unroll
        for (int qi = 0; qi < 4; ++qi)
            red2[(wr * 64 + qi * 16 + lr) * 4 + wk] = sm[qi];
    }
    __syncthreads();
#pragma unroll
    for (int qi = 0; qi < 4; ++qi) {
        const int row = wr * 64 + qi * 16 + lr;
        const float rs = 1.0f / (red2[row * 4 + 0] + red2[row * 4 + 1]
                               + red2[row * 4 + 2] + red2[row * 4 + 3]);
#pragma unroll
        for (int ki = 0; ki < 4; ++ki)
#pragma unroll
            for (int r = 0; r < 4; ++r) acc[ki][qi][r] *= rs;
    }
    __syncthreads();   // red/red2 region about to be overwritten by Vc

    // ---- PV: out[q=128][NV] = probs @ V, k loop in 4 chunks of 64 --------
    f32x4 opv[4][NVT] = {};
    for (int c = 0; c < 4; ++c) {
        // pack + write V chunk c from prefetched regs
        {
            union { uint2 q2[8]; u16 s[32]; } uq;
#pragma unroll
            for (int i = 0; i < 8; ++i) uq.q2[i] = vreg[i];
#pragma unroll
            for (int j = 0; j < 4; ++j) {
                const int row = n4 + j;
                const u32 v0 = (u32)uq.s[j]      | ((u32)uq.s[4 + j]  << 16);
                const u32 v1 = (u32)uq.s[8 + j]  | ((u32)uq.s[12 + j] << 16);
                const u32 v2 = (u32)uq.s[16 + j] | ((u32)uq.s[20 + j] << 16);
                const u32 v3 = (u32)uq.s[24 + j] | ((u32)uq.s[28 + j] << 16);
                const int slot = (t >> 6) ^ (row & 7);
                *reinterpret_cast<uint4*>(&Vc[row * 64 + (slot << 3)]) =
                    make_uint4(v0, v1, v2, v3);
            }
            if (NVT == 5 && t < 128) {
                union { uint2 q2[8]; u16 s[32]; } ub;
#pragma unroll
                for (int i = 0; i < 8; ++i) ub.q2[i] = vtail[i];
#pragma unroll
                for (int j = 0; j < 4; ++j) {
                    const int row = n4b + j;
                    const u32 v0 = (u32)ub.s[j]      | ((u32)ub.s[4 + j]  << 16);
                    const u32 v1 = (u32)ub.s[8 + j]  | ((u32)ub.s[12 + j] << 16);
                    const u32 v2 = (u32)ub.s[16 + j] | ((u32)ub.s[20 + j] << 16);
                    const u32 v3 = (u32)ub.s[24 + j] | ((u32)ub.s[28 + j] << 16);
                    const int slot = (t >> 4) ^ (row & 7);
                    *reinterpret_cast<uint4*>(&Vc[row * 64 + (slot << 3)]) =
                        make_uint4(v0, v1, v2, v3);
                }
            }
        }
        // owning waves write this chunk's probs (k-contiguous b64 packs)
        if (wk == c) {
#pragma unroll
            for (int qi = 0; qi < 4; ++qi) {
                const int qrow = wr * 64 + qi * 16 + lr;
#pragma unroll
                for (int ki = 0; ki < 4; ++ki) {
                    const u32 lo = (u32)f2bf(acc[ki][qi][0]) | ((u32)f2bf(acc[ki][qi][1]) << 16);
                    const u32 hi = (u32)f2bf(acc[ki][qi][2]) | ((u32)f2bf(acc[ki][qi][3]) << 16);
                    const int slot = ((ki << 1) + (lg >> 1)) ^ (qrow & 7);
                    *reinterpret_cast<uint2*>(
                        (char*)Pc + qrow * 128 + (slot << 4) + ((lg & 1) << 3)) =
                        make_uint2(lo, hi);
                }
            }
        }
        // T14: issue next chunk's V loads before this chunk's MFMA
        if (c < 3) {
#pragma unroll
            for (int i = 0; i < 8; ++i)
                vreg[i] = *reinterpret_cast<const uint2*>(
                    Vp + (long long)((c + 1) * 64 + k8v + i) * ldv + n4);
            if (NVT == 5 && t < 128) {
#pragma unroll
                for (int i = 0; i < 8; ++i)
                    vtail[i] = *reinterpret_cast<const uint2*>(
                        Vp + (long long)((c + 1) * 64 + k8b + i) * ldv + n4b);
            }
        }
        __syncthreads();
#pragma unroll
        for (int kk = 0; kk < 2; ++kk) {
            bf16x8 pa[4], vb[NVT];
#pragma unroll
            for (int qi = 0; qi < 4; ++qi) {
                const int row = wr2 * 64 + qi * 16 + lr;
                const int slot = ((kk << 2) + lg) ^ (row & 7);
                pa[qi] = *reinterpret_cast<const bf16x8*>(&Pc[row * 64 + (slot << 3)]);
            }
#pragma unroll
            for (int vi = 0; vi < NVT; ++vi) {
                const int row = wc * (NVT * 16) + vi * 16 + lr;
                const int slot = ((kk << 2) + lg) ^ (row & 7);
                vb[vi] = *reinterpret_cast<const bf16x8*>(&Vc[row * 64 + (slot << 3)]);
            }
#pragma unroll
            for (int qi = 0; qi < 4; ++qi)
#pragma unroll
                for (int vi = 0; vi < NVT; ++vi)
                    opv[qi][vi] = __builtin_amdgcn_mfma_f32_16x16x32_bf16(
                        pa[qi], vb[vi], opv[qi][vi], 0, 0, 0);
        }
        __syncthreads();
    }

    // ---- write out --------------------------------------------------------
#pragma unroll
    for (int qi = 0; qi < 4; ++qi)
#pragma unroll
        for (int vi = 0; vi < NVT; ++vi) {
            const int gc = wc * (NVT * 16) + vi * 16 + lr;
            if (gc >= Nwrite) continue;
#pragma unroll
            for (int r = 0; r < 4; ++r) {
                const int qrow = wr2 * 64 + qi * 16 + (lg << 2) + r;
                Cp[(long long)qrow * ldc + gc] = f2bf(opv[qi][vi][r]);
            }
        }
}

// ---------------------------------------------------------------------------
// merged: masks (tf.sequence_mask of count_nonzero) + POOL zeroing
// blocks 0..127 -> x1/M1f + zero POOL ; blocks 128..255 -> x2/M2f
// ---------------------------------------------------------------------------
__global__ __launch_bounds__(256)
void prep_small(const int* __restrict__ x1, const int* __restrict__ x2,
                float* __restrict__ M1f, float* __restrict__ POOL)
{
    const int blk = blockIdx.x;
    const int b = blk & 127;
    const int t = threadIdx.x;
    const int* x = (blk < 128) ? x1 : x2;
    float* mask = M1f + (blk < 128 ? 0 : 32768);
    int nz = (x[b * LSEQ + t] != 0) ? 1 : 0;
#pragma unroll
    for (int o = 32; o; o >>= 1) nz += __shfl_xor(nz, o, 64);
    __shared__ int red[4];
    if ((t & 63) == 0) red[t >> 6] = nz;
    __syncthreads();
    const int size = red[0] + red[1] + red[2] + red[3];
    mask[b * LSEQ + t] = (t < size) ? 1.0f : 0.0f;
    if (blk < 128) {
        for (int i = t; i < 800; i += 256) POOL[b * 800 + i] = 0.f;
    }
}

// ---------------------------------------------------------------------------
// merged weight prep: dst[n][k] (bf16) = src[srcRow(k)][n] or 0, 4 tables.
// ---------------------------------------------------------------------------
__global__ __launch_bounds__(256)
void prep_weights(const float* __restrict__ Wi, const float* __restrict__ Wa,
                  const float* __restrict__ Wp, const float* __restrict__ Wc,
                  u16* __restrict__ WiT, u16* __restrict__ WaT,
                  u16* __restrict__ WpT, u16* __restrict__ WcT)
{
    int idx = blockIdx.x * 256 + threadIdx.x;
    const float* src; u16* dst; int srcRows, srcCols, dstCols, seg1, seg2;
    if (idx < 81920)       { src = Wi; dst = WiT; srcRows = 300; srcCols = 200; dstCols = 320; seg1 = 300; seg2 = 320; }
    else if (idx < 147456) { idx -= 81920;  src = Wa; dst = WaT; srcRows = 200; srcCols = 200; dstCols = 256; seg1 = 200; seg2 = 256; }
    else if (idx < 311296) { idx -= 147456; src = Wp; dst = WpT; srcRows = 600; srcCols = 200; dstCols = 640; seg1 = 300; seg2 = 320; }
    else                   { idx -= 311296; src = Wc; dst = WcT; srcRows = 400; srcCols = 400; dstCols = 448; seg1 = 400; seg2 = 448; }
    const int n = idx / dstCols, k = idx - n * dstCols;
    int sr = -1;
    if (k < seg1) sr = k;
    else if (k >= seg2 && (k - seg2) < (srcRows - seg1)) sr = seg1 + (k - seg2);
    u16 v = 0;
    if (n < srcCols && sr >= 0) v = f2bf(src[(long long)sr * srcCols + n]);
    dst[idx] = v;
}

// ---------------------------------------------------------------------------
// merged gather + L2-normalize (both sides) -> h[row][0:320] bf16, pitch 640
// ---------------------------------------------------------------------------
__global__ __launch_bounds__(256)
void gather_norm(const int* __restrict__ x1, const int* __restrict__ x2,
                 const float* __restrict__ emb, u16* __restrict__ h)
{
    const int t = threadIdx.x;
    const int lane = t & 63;
    const long long row = (long long)blockIdx.x * 4 + (t >> 6);
    const int tok = (row < 32768) ? x1[row] : x2[row - 32768];
    const float* er = emb + (long long)tok * 300;
    float vals[5];
    float ss = 0.f;
#pragma unroll
    for (int i = 0; i < 5; ++i) {
        const int c = lane + i * 64;
        const float v = (c < 300) ? er[c] : 0.f;
        vals[i] = v;
        ss = fmaf(v, v, ss);
    }
#pragma unroll
    for (int o = 32; o; o >>= 1) ss += __shfl_xor(ss, o, 64);
    const float inv = 1.0f / sqrtf(ss);
    u16* out = h + row * 640;
#pragma unroll
    for (int i = 0; i < 5; ++i) {
        const int c = lane + i * 64;
        out[c] = f2bf(vals[i] * inv);
    }
}

__global__ __launch_bounds__(256)
void final_fc(const float* __restrict__ pooled, const float* __restrict__ Wg,
              const float* __restrict__ bg, float* __restrict__ out)
{
    const int b = blockIdx.x;
    const int t = threadIdx.x;
    float a0 = 0.f, a1 = 0.f, a2 = 0.f;
    for (int k = t; k < 800; k += 256) {
        const float p = pooled[(long long)b * 800 + k];
        a0 = fmaf(p, Wg[k * 3 + 0], a0);
        a1 = fmaf(p, Wg[k * 3 + 1], a1);
        a2 = fmaf(p, Wg[k * 3 + 2], a2);
    }
#pragma unroll
    for (int o = 32; o; o >>= 1) {
        a0 += __shfl_xor(a0, o, 64);
        a1 += __shfl_xor(a1, o, 64);
        a2 += __shfl_xor(a2, o, 64);
    }
    __shared__ float r0[4], r1[4], r2[4];
    if ((t & 63) == 0) { r0[t >> 6] = a0; r1[t >> 6] = a1; r2[t >> 6] = a2; }
    __syncthreads();
    if (t == 0) {
        out[b * 3 + 0] = r0[0] + r0[1] + r0[2] + r0[3] + bg[0];
        out[b * 3 + 1] = r1[0] + r1[1] + r1[2] + r1[3] + bg[1];
        out[b * 3 + 2] = r2[0] + r2[1] + r2[2] + r2[3] + bg[2];
    }
}

// ---------------------------------------------------------------------------
extern "C" void kernel_launch(void* const* d_in, const int* in_sizes, int n_in,
                              void* d_out, int out_size, void* d_ws, size_t ws_size,
                              hipStream_t stream)
{
    (void)in_sizes; (void)n_in; (void)out_size; (void)ws_size;

    const int*   x1     = (const int*)  d_in[0];
    const int*   x2     = (const int*)  d_in[1];
    const float* emb    = (const float*)d_in[2];
    const float* Wi     = (const float*)d_in[3];
    const float* bi     = (const float*)d_in[4];
    const float* b_dist = (const float*)d_in[5];
    const float* Wp     = (const float*)d_in[6];
    const float* bp     = (const float*)d_in[7];
    const float* Wa     = (const float*)d_in[8];
    const float* ba     = (const float*)d_in[9];
    const float* Wc     = (const float*)d_in[10];
    const float* bc     = (const float*)d_in[11];
    const float* Wg     = (const float*)d_in[12];
    const float* bg     = (const float*)d_in[13];
    float* out = (float*)d_out;

    // ---- workspace (bf16 u16 unless noted) -------------------------------
    u16* wsu  = (u16*)d_ws;
    u16* H    = wsu;                       // [65536][640] e|0|xp|0
    u16* CMP  = wsu + 41943040;            // [65536][448] P|beta/alpha|0
    u16* FA   = wsu + 71303168;            // [65536][256] f / a
    u16* WiT  = wsu + 88080384;            // [256][320]
    u16* WaT  = wsu + 88162304;            // [256][256]
    u16* WpT  = wsu + 88227840;            // [256][640]
    u16* WcT  = wsu + 88391680;            // [512][448]
    float* fb = (float*)(wsu + 88621056);
    float* POOL = fb;                      // [128][800]
    float* M1f  = fb + 102400;             // [128][256]; M2f = M1f + 32768
    float* M2f  = fb + 135168;

    u16* CMP2 = CMP + (long long)32768 * 448;

    prep_small<<<256, 256, 0, stream>>>(x1, x2, M1f, POOL);
    prep_weights<<<2112, 256, 0, stream>>>(Wi, Wa, Wp, Wc, WiT, WaT, WpT, WcT);
    gather_norm<<<16384, 256, 0, stream>>>(x1, x2, emb, H);

    // f = relu(e @ Wi + bi), both sides -> FA
    gemm<0, true, true><<<dim3(1, 512, 1), 512, 0, stream>>>(
        H, 640, WiT, 320, FA, 256, bi, 200, nullptr, nullptr, 320, 256);
    // fused intra attention: xp = softmax(f@f^T + dbias) @ e -> H cols 320:640
    fattn<0><<<512, 512, 0, stream>>>(FA, H, nullptr, nullptr, nullptr, nullptr, b_dist);
    // P = h @ Wp + bp -> CMP cols 0:256
    gemm<0, true, false><<<dim3(1, 512, 1), 512, 0, stream>>>(
        H, 640, WpT, 640, CMP, 448, bp, 200, nullptr, nullptr, 640, 256);
    // a = relu(P @ Wa + ba) -> FA
    gemm<0, true, true><<<dim3(1, 512, 1), 512, 0, stream>>>(
        CMP, 448, WaT, 256, FA, 256, ba, 200, nullptr, nullptr, 256, 256);
    // fused cross attention: beta/alpha -> CMP/CMP2 cols 200:448
    fattn<1><<<512, 512, 0, stream>>>(FA, nullptr, CMP, CMP2, M1f, M2f, nullptr);
    // compare + masked pool, both sides
    gemm<2, true, true><<<dim3(2, 512, 1), 512, 0, stream>>>(
        CMP, 448, WcT, 448, nullptr, 0, bc, 400, POOL, M1f, 448, 400);

    final_fc<<<NB, 256, 0, stream>>>(POOL, Wg, bg, out);
}